// Round 1
// baseline (2591.884 us; speedup 1.0000x reference)
//
#include <hip/hip_runtime.h>

#define B_ 8
#define IMGSZ 224
#define PATCH 16
#define D_ 192
#define DEPTH_ 8
#define H_ 14
#define W_ 14
#define L_ 196
#define DIN 384
#define DSTATE 16
#define DCONV 4
#define DTR 12
#define NCLS_ 1000
#define EPS_ 1e-5f
#define ROWS_PER_DIR (B_*L_)      /* 1568 */
#define M_TOTAL (4*ROWS_PER_DIR)  /* 6272 */

// ---------------- patch embed + pe LayerNorm + build 4 directional seqs ----
__global__ __launch_bounds__(256) void k_patch(
    const float* __restrict__ x, const float* __restrict__ pw, const float* __restrict__ pb,
    const float* __restrict__ plw, const float* __restrict__ plb,
    float* __restrict__ hidden, float* __restrict__ residual)
{
  int blk = blockIdx.x;             // B*L
  int b = blk / L_, l = blk % L_;
  int hh = l / W_, ww = l % W_;
  __shared__ float patch[768];
  __shared__ float vals[D_];
  int tid = threadIdx.x;
  for (int i = tid; i < 768; i += 256) {
    int c = i >> 8, rem = i & 255, pi = rem >> 4, pj = rem & 15;
    patch[i] = x[(((size_t)b*3 + c)*IMGSZ + hh*PATCH + pi)*IMGSZ + ww*PATCH + pj];
  }
  __syncthreads();
  if (tid < D_) {
    const float* wr = pw + (size_t)tid*768;
    float acc = pb[tid];
    #pragma unroll 4
    for (int i = 0; i < 768; ++i) acc += patch[i]*wr[i];
    vals[tid] = acc;
  }
  __syncthreads();
  if (tid < D_) {
    float m = 0.f;
    for (int j = 0; j < D_; ++j) m += vals[j];
    m *= (1.f/D_);
    float var = 0.f;
    for (int j = 0; j < D_; ++j) { float dd = vals[j]-m; var += dd*dd; }
    var *= (1.f/D_);
    float nv = (vals[tid]-m)*rsqrtf(var+EPS_)*plw[tid] + plb[tid];
    int l1 = ww*W_ + hh;
    size_t r0 = ((size_t)(0*B_+b))*L_ + l;
    size_t r1 = ((size_t)(1*B_+b))*L_ + l1;
    size_t r2 = ((size_t)(2*B_+b))*L_ + (L_-1-l);
    size_t r3 = ((size_t)(3*B_+b))*L_ + (L_-1-l1);
    hidden[r0*D_+tid]=nv; hidden[r1*D_+tid]=nv; hidden[r2*D_+tid]=nv; hidden[r3*D_+tid]=nv;
    residual[r0*D_+tid]=0.f; residual[r1*D_+tid]=0.f; residual[r2*D_+tid]=0.f; residual[r3*D_+tid]=0.f;
  }
}

// ---------------- residual += hidden; xln = LN(residual)*w+b ---------------
__global__ __launch_bounds__(256) void k_ln_res(
    const float* __restrict__ lnw, const float* __restrict__ lnb,
    const float* __restrict__ hidden, float* __restrict__ residual,
    float* __restrict__ xln, int layer)
{
  int row = blockIdx.x*4 + (threadIdx.x >> 6);
  int lane = threadIdx.x & 63;
  int kdir = row / ROWS_PER_DIR;
  const float* w  = lnw + (size_t)(kdir*DEPTH_+layer)*D_;
  const float* bb = lnb + (size_t)(kdir*DEPTH_+layer)*D_;
  size_t base = (size_t)row*D_;
  float v[3]; float s = 0.f;
  #pragma unroll
  for (int i=0;i<3;i++){
    int d = lane + i*64;
    float t = residual[base+d] + hidden[base+d];
    residual[base+d] = t;
    v[i] = t; s += t;
  }
  #pragma unroll
  for (int off=32;off;off>>=1) s += __shfl_xor(s,off);
  float m = s*(1.f/D_);
  float q = 0.f;
  #pragma unroll
  for (int i=0;i<3;i++){ float dd = v[i]-m; q += dd*dd; }
  #pragma unroll
  for (int off=32;off;off>>=1) q += __shfl_xor(q,off);
  float inv = rsqrtf(q*(1.f/D_)+EPS_);
  #pragma unroll
  for (int i=0;i<3;i++){ int d = lane+i*64; xln[base+d] = (v[i]-m)*inv*w[d]+bb[d]; }
}

// ---------------- generic tiled GEMM: C[M,N] = X[M,K] * W[N,K]^T ----------
// weights per direction: Wp = Wl + kdir*wstride; rows grouped (1568 per dir, 32 | 1568)
__global__ __launch_bounds__(256) void k_gemm(
    const float* __restrict__ X, const float* __restrict__ Wl,
    float* __restrict__ C, int N, int K, int wstride)
{
  __shared__ float Xst[32][36];   // [kk][row]
  __shared__ float Wst[32][68];   // [kk][col]
  int row0 = blockIdx.x*32, col0 = blockIdx.y*64;
  int kdir = row0 / ROWS_PER_DIR;
  const float* Wp = Wl + (size_t)kdir*wstride;
  int tid = threadIdx.x;
  int ty = tid >> 4, tx = tid & 15;
  float acc[2][4] = {{0.f,0.f,0.f,0.f},{0.f,0.f,0.f,0.f}};
  for (int k0 = 0; k0 < K; k0 += 32) {
    {
      int idx = tid*4;
      int r = idx >> 5, kk = idx & 31;
      float4 v = *reinterpret_cast<const float4*>(&X[(size_t)(row0+r)*K + k0 + kk]);
      Xst[kk+0][r]=v.x; Xst[kk+1][r]=v.y; Xst[kk+2][r]=v.z; Xst[kk+3][r]=v.w;
    }
    #pragma unroll
    for (int hf = 0; hf < 2; ++hf) {
      int idx = tid*4 + hf*1024;
      int c = idx >> 5, kk = idx & 31;
      float4 v = *reinterpret_cast<const float4*>(&Wp[(size_t)(col0+c)*K + k0 + kk]);
      Wst[kk+0][c]=v.x; Wst[kk+1][c]=v.y; Wst[kk+2][c]=v.z; Wst[kk+3][c]=v.w;
    }
    __syncthreads();
    #pragma unroll
    for (int kk = 0; kk < 32; ++kk) {
      float x0 = Xst[kk][ty*2+0];
      float x1 = Xst[kk][ty*2+1];
      const float4 wv = *reinterpret_cast<const float4*>(&Wst[kk][tx*4]);
      acc[0][0] += x0*wv.x; acc[0][1] += x0*wv.y; acc[0][2] += x0*wv.z; acc[0][3] += x0*wv.w;
      acc[1][0] += x1*wv.x; acc[1][1] += x1*wv.y; acc[1][2] += x1*wv.z; acc[1][3] += x1*wv.w;
    }
    __syncthreads();
  }
  #pragma unroll
  for (int i = 0; i < 2; ++i) {
    float4 o = make_float4(acc[i][0],acc[i][1],acc[i][2],acc[i][3]);
    *reinterpret_cast<float4*>(&C[(size_t)(row0+ty*2+i)*N + col0 + tx*4]) = o;
  }
}

// ---------------- causal depthwise conv (k=4) + bias + SiLU ---------------
__global__ __launch_bounds__(256) void k_conv(
    const float* __restrict__ xz, const float* __restrict__ cw, const float* __restrict__ cb,
    float* __restrict__ u, int layer)
{
  int idx = blockIdx.x*256 + threadIdx.x;
  if (idx >= M_TOTAL*DIN) return;
  int row = idx / DIN, d = idx - row*DIN;
  int kdir = row / ROWS_PER_DIR;
  int l = row % L_;
  const float* cwp = cw + ((size_t)(kdir*DEPTH_+layer)*DIN + d)*DCONV;
  float acc = cb[(size_t)(kdir*DEPTH_+layer)*DIN + d];
  #pragma unroll
  for (int t = 0; t < DCONV; ++t) {
    int ll = l - 3 + t;
    if (ll >= 0) acc += xz[((size_t)row + (ll - l))*768 + d] * cwp[t];
  }
  u[idx] = acc / (1.f + expf(-acc));   // SiLU
}

// ---------------- x_proj: xdbl[row,0:44] = u_row @ x_proj_w^T -------------
__global__ __launch_bounds__(64) void k_xproj(
    const float* __restrict__ u, const float* __restrict__ xw,
    float* __restrict__ xdbl, int layer)
{
  int row = blockIdx.x;
  int kdir = row / ROWS_PER_DIR;
  __shared__ float us[DIN];
  int lane = threadIdx.x;
  for (int i = lane; i < DIN; i += 64) us[i] = u[(size_t)row*DIN + i];
  __syncthreads();
  if (lane < 44) {
    const float* wr = xw + ((size_t)(kdir*DEPTH_+layer)*44 + lane)*DIN;
    float acc = 0.f;
    for (int dd = 0; dd < DIN; dd += 4) {
      float4 a4 = *reinterpret_cast<const float4*>(&us[dd]);
      float4 b4 = *reinterpret_cast<const float4*>(&wr[dd]);
      acc += a4.x*b4.x + a4.y*b4.y + a4.z*b4.z + a4.w*b4.w;
    }
    xdbl[(size_t)row*44 + lane] = acc;
  }
}

// ---------------- delta = softplus(dt @ dt_w^T + dt_b) --------------------
__global__ __launch_bounds__(256) void k_delta(
    const float* __restrict__ xdbl, const float* __restrict__ dtw, const float* __restrict__ dtb,
    float* __restrict__ delta, int layer)
{
  int idx = blockIdx.x*256 + threadIdx.x;
  if (idx >= M_TOTAL*DIN) return;
  int row = idx / DIN, d = idx - row*DIN;
  int kdir = row / ROWS_PER_DIR;
  const float* xr = xdbl + (size_t)row*44;
  const float* wr = dtw + ((size_t)(kdir*DEPTH_+layer)*DIN + d)*DTR;
  float acc = dtb[(size_t)(kdir*DEPTH_+layer)*DIN + d];
  #pragma unroll
  for (int j = 0; j < DTR; ++j) acc += xr[j]*wr[j];
  delta[idx] = (acc > 20.f) ? acc : log1pf(expf(acc));
}

// ---------------- selective scan + skip(D) + SiLU(z) gate -----------------
// block: 16 channels x 16 states; grid: 4*8*24
__global__ __launch_bounds__(256) void k_scan(
    const float* __restrict__ delta, const float* __restrict__ u,
    const float* __restrict__ xdbl, const float* __restrict__ xz,
    const float* __restrict__ Alog, const float* __restrict__ Dp,
    float* __restrict__ yg, int layer)
{
  int blk = blockIdx.x;
  int kdir = blk / (B_*24);
  int rem = blk % (B_*24);
  int b = rem / 24, dc = rem % 24;
  int lane16 = threadIdx.x & 15, dloc = threadIdx.x >> 4;
  int d = dc*16 + dloc;
  size_t pl = (size_t)(kdir*DEPTH_+layer)*DIN + d;
  float a = -expf(Alog[pl*DSTATE + lane16]);
  float Dv = Dp[pl];
  size_t rowbase = ((size_t)kdir*B_ + b)*L_;
  float h = 0.f;
  for (int l = 0; l < L_; ++l) {
    size_t row = rowbase + l;
    float dl = delta[row*DIN + d];
    float ul = u[row*DIN + d];
    float Bv = xdbl[row*44 + DTR + lane16];
    float Cv = xdbl[row*44 + DTR + DSTATE + lane16];
    h = h * __expf(dl*a) + dl*ul*Bv;
    float p = h * Cv;
    p += __shfl_xor(p, 1, 16);
    p += __shfl_xor(p, 2, 16);
    p += __shfl_xor(p, 4, 16);
    p += __shfl_xor(p, 8, 16);
    if (lane16 == 0) {
      float z = xz[row*768 + DIN + d];
      yg[row*DIN + d] = (p + ul*Dv) * (z / (1.f + __expf(-z)));
    }
  }
}

// ---------------- merge 4 directions + out_norm LN + head LN --------------
__global__ __launch_bounds__(64) void k_combine(
    const float* __restrict__ hid, const float* __restrict__ res,
    const float* __restrict__ onw, const float* __restrict__ onb,
    const float* __restrict__ hlw, const float* __restrict__ hlb,
    float* __restrict__ ynorm)
{
  int blk = blockIdx.x;
  int b = blk / L_, l = blk % L_;
  int hh = l / W_, ww = l % W_;
  int l1 = ww*W_ + hh;
  size_t r0 = ((size_t)(0*B_+b))*L_ + l;
  size_t r1 = ((size_t)(1*B_+b))*L_ + l1;
  size_t r2 = ((size_t)(2*B_+b))*L_ + (L_-1-l);
  size_t r3 = ((size_t)(3*B_+b))*L_ + (L_-1-l1);
  int lane = threadIdx.x;
  float v[3]; float s = 0.f;
  #pragma unroll
  for (int i=0;i<3;i++){
    int d = lane + i*64;
    float t = hid[r0*D_+d]+res[r0*D_+d] + hid[r1*D_+d]+res[r1*D_+d]
            + hid[r2*D_+d]+res[r2*D_+d] + hid[r3*D_+d]+res[r3*D_+d];
    v[i]=t; s+=t;
  }
  #pragma unroll
  for (int off=32;off;off>>=1) s += __shfl_xor(s,off);
  float m = s*(1.f/D_); float q=0.f;
  #pragma unroll
  for (int i=0;i<3;i++){ float dd=v[i]-m; q+=dd*dd; }
  #pragma unroll
  for (int off=32;off;off>>=1) q += __shfl_xor(q,off);
  float inv = rsqrtf(q*(1.f/D_)+EPS_);
  float v2[3]; s = 0.f;
  #pragma unroll
  for (int i=0;i<3;i++){ int d=lane+i*64; float t=(v[i]-m)*inv*onw[d]+onb[d]; v2[i]=t; s+=t; }
  #pragma unroll
  for (int off=32;off;off>>=1) s += __shfl_xor(s,off);
  float m2 = s*(1.f/D_); q=0.f;
  #pragma unroll
  for (int i=0;i<3;i++){ float dd=v2[i]-m2; q+=dd*dd; }
  #pragma unroll
  for (int off=32;off;off>>=1) q += __shfl_xor(q,off);
  float inv2 = rsqrtf(q*(1.f/D_)+EPS_);
  #pragma unroll
  for (int i=0;i<3;i++){ int d=lane+i*64; ynorm[((size_t)b*L_+l)*D_+d] = (v2[i]-m2)*inv2*hlw[d]+hlb[d]; }
}

// ---------------- mean over L (deterministic, no atomics) -----------------
__global__ __launch_bounds__(192) void k_mean(const float* __restrict__ ynorm, float* __restrict__ ybar)
{
  int b = blockIdx.x, d = threadIdx.x;
  float s = 0.f;
  for (int l = 0; l < L_; ++l) s += ynorm[((size_t)b*L_+l)*D_ + d];
  ybar[b*D_+d] = s * (1.f/L_);
}

// ---------------- classifier head -----------------------------------------
__global__ __launch_bounds__(256) void k_head(
    const float* __restrict__ ybar, const float* __restrict__ hw, const float* __restrict__ hb,
    float* __restrict__ out)
{
  __shared__ float ys[D_];
  int b = blockIdx.x >> 2;
  int c = (blockIdx.x & 3)*256 + threadIdx.x;
  for (int i = threadIdx.x; i < D_; i += 256) ys[i] = ybar[b*D_+i];
  __syncthreads();
  if (c < NCLS_) {
    float acc = hb[c];
    const float* wr = hw + (size_t)c*D_;
    for (int dd = 0; dd < D_; dd += 4) {
      float4 a4 = *reinterpret_cast<const float4*>(&ys[dd]);
      float4 b4 = *reinterpret_cast<const float4*>(&wr[dd]);
      acc += a4.x*b4.x + a4.y*b4.y + a4.z*b4.z + a4.w*b4.w;
    }
    out[(size_t)b*NCLS_ + c] = acc;
  }
}

extern "C" void kernel_launch(void* const* d_in, const int* in_sizes, int n_in,
                              void* d_out, int out_size, void* d_ws, size_t ws_size,
                              hipStream_t stream)
{
  const float* x          = (const float*)d_in[0];
  const float* patch_w    = (const float*)d_in[1];
  const float* patch_b    = (const float*)d_in[2];
  const float* pe_ln_w    = (const float*)d_in[3];
  const float* pe_ln_b    = (const float*)d_in[4];
  const float* ln_w       = (const float*)d_in[5];
  const float* ln_b       = (const float*)d_in[6];
  const float* in_proj_w  = (const float*)d_in[7];
  const float* conv_w     = (const float*)d_in[8];
  const float* conv_b     = (const float*)d_in[9];
  const float* x_proj_w   = (const float*)d_in[10];
  const float* dt_w       = (const float*)d_in[11];
  const float* dt_b       = (const float*)d_in[12];
  const float* A_log      = (const float*)d_in[13];
  const float* Dp         = (const float*)d_in[14];
  const float* out_proj_w = (const float*)d_in[15];
  const float* out_norm_w = (const float*)d_in[16];
  const float* out_norm_b = (const float*)d_in[17];
  const float* head_ln_w  = (const float*)d_in[18];
  const float* head_ln_b  = (const float*)d_in[19];
  const float* head_w     = (const float*)d_in[20];
  const float* head_b     = (const float*)d_in[21];
  float* out = (float*)d_out;

  float* ws = (float*)d_ws;
  float* hidden   = ws;                    // 1,204,224
  float* residual = hidden   + 1204224;    // 1,204,224
  float* xln      = residual + 1204224;    // 1,204,224
  float* xz       = xln      + 1204224;    // 4,816,896
  float* u        = xz       + 4816896;    // 2,408,448
  float* xdbl     = u        + 2408448;    //   275,968
  float* delta    = xdbl     + 275968;     // 2,408,448
  float* yg       = delta    + 2408448;    // 2,408,448
  float* ynorm    = yg       + 2408448;    //   301,056
  float* ybar     = ynorm    + 301056;     //     1,536
  // total ~ 62 MB f32 workspace

  k_patch<<<B_*L_, 256, 0, stream>>>(x, patch_w, patch_b, pe_ln_w, pe_ln_b, hidden, residual);

  for (int layer = 0; layer < DEPTH_; ++layer) {
    k_ln_res<<<M_TOTAL/4, 256, 0, stream>>>(ln_w, ln_b, hidden, residual, xln, layer);
    k_gemm<<<dim3(M_TOTAL/32, 768/64), 256, 0, stream>>>(
        xln, in_proj_w + (size_t)layer*768*D_, xz, 768, D_, DEPTH_*768*D_);
    k_conv<<<(M_TOTAL*DIN+255)/256, 256, 0, stream>>>(xz, conv_w, conv_b, u, layer);
    k_xproj<<<M_TOTAL, 64, 0, stream>>>(u, x_proj_w, xdbl, layer);
    k_delta<<<(M_TOTAL*DIN+255)/256, 256, 0, stream>>>(xdbl, dt_w, dt_b, delta, layer);
    k_scan<<<4*B_*24, 256, 0, stream>>>(delta, u, xdbl, xz, A_log, Dp, yg, layer);
    k_gemm<<<dim3(M_TOTAL/32, D_/64), 256, 0, stream>>>(
        yg, out_proj_w + (size_t)layer*D_*DIN, hidden, D_, DIN, DEPTH_*D_*DIN);
  }

  k_combine<<<B_*L_, 64, 0, stream>>>(hidden, residual, out_norm_w, out_norm_b,
                                      head_ln_w, head_ln_b, ynorm);
  k_mean<<<B_, 192, 0, stream>>>(ynorm, ybar);
  k_head<<<B_*4, 256, 0, stream>>>(ybar, head_w, head_b, out);
}

// Round 2
// 1861.515 us; speedup vs baseline: 1.3924x; 1.3924x over previous
//
#include <hip/hip_runtime.h>

#define B_ 8
#define IMGSZ 224
#define PATCH 16
#define D_ 192
#define DEPTH_ 8
#define H_ 14
#define W_ 14
#define L_ 196
#define DIN 384
#define DSTATE 16
#define DCONV 4
#define DTR 12
#define NCLS_ 1000
#define EPS_ 1e-5f
#define ROWS_PER_DIR (B_*L_)      /* 1568 */
#define M_TOTAL (4*ROWS_PER_DIR)  /* 6272 */

// ---------------- patch embed + pe LayerNorm + build 4 directional seqs ----
__global__ __launch_bounds__(256) void k_patch(
    const float* __restrict__ x, const float* __restrict__ pw, const float* __restrict__ pb,
    const float* __restrict__ plw, const float* __restrict__ plb,
    float* __restrict__ hidden, float* __restrict__ residual)
{
  int blk = blockIdx.x;             // B*L
  int b = blk / L_, l = blk % L_;
  int hh = l / W_, ww = l % W_;
  __shared__ float patch[768];
  __shared__ float vals[D_];
  int tid = threadIdx.x;
  for (int i = tid; i < 768; i += 256) {
    int c = i >> 8, rem = i & 255, pi = rem >> 4, pj = rem & 15;
    patch[i] = x[(((size_t)b*3 + c)*IMGSZ + hh*PATCH + pi)*IMGSZ + ww*PATCH + pj];
  }
  __syncthreads();
  if (tid < D_) {
    const float* wr = pw + (size_t)tid*768;
    float acc = pb[tid];
    #pragma unroll 4
    for (int i = 0; i < 768; ++i) acc += patch[i]*wr[i];
    vals[tid] = acc;
  }
  __syncthreads();
  if (tid < D_) {
    float m = 0.f;
    for (int j = 0; j < D_; ++j) m += vals[j];
    m *= (1.f/D_);
    float var = 0.f;
    for (int j = 0; j < D_; ++j) { float dd = vals[j]-m; var += dd*dd; }
    var *= (1.f/D_);
    float nv = (vals[tid]-m)*rsqrtf(var+EPS_)*plw[tid] + plb[tid];
    int l1 = ww*W_ + hh;
    size_t r0 = ((size_t)(0*B_+b))*L_ + l;
    size_t r1 = ((size_t)(1*B_+b))*L_ + l1;
    size_t r2 = ((size_t)(2*B_+b))*L_ + (L_-1-l);
    size_t r3 = ((size_t)(3*B_+b))*L_ + (L_-1-l1);
    hidden[r0*D_+tid]=nv; hidden[r1*D_+tid]=nv; hidden[r2*D_+tid]=nv; hidden[r3*D_+tid]=nv;
    residual[r0*D_+tid]=0.f; residual[r1*D_+tid]=0.f; residual[r2*D_+tid]=0.f; residual[r3*D_+tid]=0.f;
  }
}

// ---------------- residual += hidden; xln = LN(residual)*w+b ---------------
__global__ __launch_bounds__(256) void k_ln_res(
    const float* __restrict__ lnw, const float* __restrict__ lnb,
    const float* __restrict__ hidden, float* __restrict__ residual,
    float* __restrict__ xln, int layer)
{
  int row = blockIdx.x*4 + (threadIdx.x >> 6);
  int lane = threadIdx.x & 63;
  int kdir = row / ROWS_PER_DIR;
  const float* w  = lnw + (size_t)(kdir*DEPTH_+layer)*D_;
  const float* bb = lnb + (size_t)(kdir*DEPTH_+layer)*D_;
  size_t base = (size_t)row*D_;
  float v[3]; float s = 0.f;
  #pragma unroll
  for (int i=0;i<3;i++){
    int d = lane + i*64;
    float t = residual[base+d] + hidden[base+d];
    residual[base+d] = t;
    v[i] = t; s += t;
  }
  #pragma unroll
  for (int off=32;off;off>>=1) s += __shfl_xor(s,off);
  float m = s*(1.f/D_);
  float q = 0.f;
  #pragma unroll
  for (int i=0;i<3;i++){ float dd = v[i]-m; q += dd*dd; }
  #pragma unroll
  for (int off=32;off;off>>=1) q += __shfl_xor(q,off);
  float inv = rsqrtf(q*(1.f/D_)+EPS_);
  #pragma unroll
  for (int i=0;i<3;i++){ int d = lane+i*64; xln[base+d] = (v[i]-m)*inv*w[d]+bb[d]; }
}

// ---------------- generic tiled GEMM: C[M,N] = X[M,K] * W[N,K]^T ----------
__global__ __launch_bounds__(256) void k_gemm(
    const float* __restrict__ X, const float* __restrict__ Wl,
    float* __restrict__ C, int N, int K, int wstride)
{
  __shared__ float Xst[32][36];   // [kk][row]
  __shared__ float Wst[32][68];   // [kk][col]
  int row0 = blockIdx.x*32, col0 = blockIdx.y*64;
  int kdir = row0 / ROWS_PER_DIR;
  const float* Wp = Wl + (size_t)kdir*wstride;
  int tid = threadIdx.x;
  int ty = tid >> 4, tx = tid & 15;
  float acc[2][4] = {{0.f,0.f,0.f,0.f},{0.f,0.f,0.f,0.f}};
  for (int k0 = 0; k0 < K; k0 += 32) {
    {
      int idx = tid*4;
      int r = idx >> 5, kk = idx & 31;
      float4 v = *reinterpret_cast<const float4*>(&X[(size_t)(row0+r)*K + k0 + kk]);
      Xst[kk+0][r]=v.x; Xst[kk+1][r]=v.y; Xst[kk+2][r]=v.z; Xst[kk+3][r]=v.w;
    }
    #pragma unroll
    for (int hf = 0; hf < 2; ++hf) {
      int idx = tid*4 + hf*1024;
      int c = idx >> 5, kk = idx & 31;
      float4 v = *reinterpret_cast<const float4*>(&Wp[(size_t)(col0+c)*K + k0 + kk]);
      Wst[kk+0][c]=v.x; Wst[kk+1][c]=v.y; Wst[kk+2][c]=v.z; Wst[kk+3][c]=v.w;
    }
    __syncthreads();
    #pragma unroll
    for (int kk = 0; kk < 32; ++kk) {
      float x0 = Xst[kk][ty*2+0];
      float x1 = Xst[kk][ty*2+1];
      const float4 wv = *reinterpret_cast<const float4*>(&Wst[kk][tx*4]);
      acc[0][0] += x0*wv.x; acc[0][1] += x0*wv.y; acc[0][2] += x0*wv.z; acc[0][3] += x0*wv.w;
      acc[1][0] += x1*wv.x; acc[1][1] += x1*wv.y; acc[1][2] += x1*wv.z; acc[1][3] += x1*wv.w;
    }
    __syncthreads();
  }
  #pragma unroll
  for (int i = 0; i < 2; ++i) {
    float4 o = make_float4(acc[i][0],acc[i][1],acc[i][2],acc[i][3]);
    *reinterpret_cast<float4*>(&C[(size_t)(row0+ty*2+i)*N + col0 + tx*4]) = o;
  }
}

// ---------------- causal depthwise conv (k=4) + bias + SiLU ---------------
__global__ __launch_bounds__(256) void k_conv(
    const float* __restrict__ xz, const float* __restrict__ cw, const float* __restrict__ cb,
    float* __restrict__ u, int layer)
{
  int idx = blockIdx.x*256 + threadIdx.x;
  if (idx >= M_TOTAL*DIN) return;
  int row = idx / DIN, d = idx - row*DIN;
  int kdir = row / ROWS_PER_DIR;
  int l = row % L_;
  const float* cwp = cw + ((size_t)(kdir*DEPTH_+layer)*DIN + d)*DCONV;
  float acc = cb[(size_t)(kdir*DEPTH_+layer)*DIN + d];
  #pragma unroll
  for (int t = 0; t < DCONV; ++t) {
    int ll = l - 3 + t;
    if (ll >= 0) acc += xz[((size_t)row + (ll - l))*768 + d] * cwp[t];
  }
  u[idx] = acc / (1.f + expf(-acc));   // SiLU
}

// ---------------- x_proj: xdbl[row,0:44] = u_row @ x_proj_w^T -------------
__global__ __launch_bounds__(64) void k_xproj(
    const float* __restrict__ u, const float* __restrict__ xw,
    float* __restrict__ xdbl, int layer)
{
  int row = blockIdx.x;
  int kdir = row / ROWS_PER_DIR;
  __shared__ float us[DIN];
  int lane = threadIdx.x;
  for (int i = lane; i < DIN; i += 64) us[i] = u[(size_t)row*DIN + i];
  __syncthreads();
  if (lane < 44) {
    const float* wr = xw + ((size_t)(kdir*DEPTH_+layer)*44 + lane)*DIN;
    float acc = 0.f;
    for (int dd = 0; dd < DIN; dd += 4) {
      float4 a4 = *reinterpret_cast<const float4*>(&us[dd]);
      float4 b4 = *reinterpret_cast<const float4*>(&wr[dd]);
      acc += a4.x*b4.x + a4.y*b4.y + a4.z*b4.z + a4.w*b4.w;
    }
    xdbl[(size_t)row*44 + lane] = acc;
  }
}

// ---------------- delta = softplus(dt @ dt_w^T + dt_b) --------------------
__global__ __launch_bounds__(256) void k_delta(
    const float* __restrict__ xdbl, const float* __restrict__ dtw, const float* __restrict__ dtb,
    float* __restrict__ delta, int layer)
{
  int idx = blockIdx.x*256 + threadIdx.x;
  if (idx >= M_TOTAL*DIN) return;
  int row = idx / DIN, d = idx - row*DIN;
  int kdir = row / ROWS_PER_DIR;
  const float* xr = xdbl + (size_t)row*44;
  const float* wr = dtw + ((size_t)(kdir*DEPTH_+layer)*DIN + d)*DTR;
  float acc = dtb[(size_t)(kdir*DEPTH_+layer)*DIN + d];
  #pragma unroll
  for (int j = 0; j < DTR; ++j) acc += xr[j]*wr[j];
  delta[idx] = (acc > 20.f) ? acc : log1pf(expf(acc));
}

// ---------------- selective scan + skip(D) + SiLU(z) gate -----------------
// block: 16 channels x 16 states; grid: 4*8*24
// Chunked LDS pipeline: stage 14 l-steps of delta/u/B/C/z per chunk,
// prefetch chunk c+1 into registers while computing chunk c from LDS.
#define SCHUNK 14
#define NCHUNK 14
__global__ __launch_bounds__(256) void k_scan(
    const float* __restrict__ delta, const float* __restrict__ u,
    const float* __restrict__ xdbl, const float* __restrict__ xz,
    const float* __restrict__ Alog, const float* __restrict__ Dp,
    float* __restrict__ yg, int layer)
{
  int blk = blockIdx.x;
  int kdir = blk / (B_*24);
  int rem = blk % (B_*24);
  int b = rem / 24, dc = rem % 24;
  int tid = threadIdx.x;
  int lane16 = tid & 15, dloc = tid >> 4;
  int d = dc*16 + dloc;
  size_t pl = (size_t)(kdir*DEPTH_+layer)*DIN + d;
  float a = -expf(Alog[pl*DSTATE + lane16]);
  float Dv = Dp[pl];
  size_t rowbase = ((size_t)kdir*B_ + b)*L_;

  __shared__ float sd[SCHUNK][16], su[SCHUNK][16], sB[SCHUNK][16],
                   sC[SCHUNK][16], sz[SCHUNK][16], sy[SCHUNK][16];

  // flat loader indexing: 224 active threads, (ll, cc)
  int ll = tid >> 4;      // 0..13 valid when tid < 224
  int cc = tid & 15;
  bool ldr = tid < 224;

  // prefetch chunk 0 into registers
  float rd = 0.f, ru = 0.f, rB = 0.f, rC = 0.f, rz = 0.f;
  if (ldr) {
    size_t r = rowbase + ll;
    rd = delta[r*DIN + dc*16 + cc];
    ru = u[r*DIN + dc*16 + cc];
    rB = xdbl[r*44 + DTR + cc];
    rC = xdbl[r*44 + DTR + DSTATE + cc];
    rz = xz[r*768 + DIN + dc*16 + cc];
  }

  float h = 0.f;
  for (int ch = 0; ch < NCHUNK; ++ch) {
    // stage registers -> LDS (prev chunk's compute & sy-store finished by syncs below)
    if (ldr) { sd[ll][cc]=rd; su[ll][cc]=ru; sB[ll][cc]=rB; sC[ll][cc]=rC; sz[ll][cc]=rz; }
    __syncthreads();
    // issue next chunk's global loads (latency hides under compute below)
    if (ch+1 < NCHUNK && ldr) {
      size_t r = rowbase + (ch+1)*SCHUNK + ll;
      rd = delta[r*DIN + dc*16 + cc];
      ru = u[r*DIN + dc*16 + cc];
      rB = xdbl[r*44 + DTR + cc];
      rC = xdbl[r*44 + DTR + DSTATE + cc];
      rz = xz[r*768 + DIN + dc*16 + cc];
    }
    // compute 14 sequential steps from LDS
    #pragma unroll
    for (int l = 0; l < SCHUNK; ++l) {
      float dl = sd[l][dloc];
      float ul = su[l][dloc];
      float Bv = sB[l][lane16];
      float Cv = sC[l][lane16];
      h = h*__expf(dl*a) + dl*ul*Bv;
      float p = h*Cv;
      p += __shfl_xor(p, 1, 16);
      p += __shfl_xor(p, 2, 16);
      p += __shfl_xor(p, 4, 16);
      p += __shfl_xor(p, 8, 16);
      if (lane16 == 0) {
        float z = sz[l][dloc];
        sy[l][dloc] = (p + ul*Dv) * (z / (1.f + __expf(-z)));
      }
    }
    __syncthreads();
    // coalesced chunk store of gated outputs
    if (ldr) yg[(rowbase + ch*SCHUNK + ll)*DIN + dc*16 + cc] = sy[ll][cc];
    __syncthreads();
  }
}

// ---------------- merge 4 directions + out_norm LN + head LN --------------
__global__ __launch_bounds__(64) void k_combine(
    const float* __restrict__ hid, const float* __restrict__ res,
    const float* __restrict__ onw, const float* __restrict__ onb,
    const float* __restrict__ hlw, const float* __restrict__ hlb,
    float* __restrict__ ynorm)
{
  int blk = blockIdx.x;
  int b = blk / L_, l = blk % L_;
  int hh = l / W_, ww = l % W_;
  int l1 = ww*W_ + hh;
  size_t r0 = ((size_t)(0*B_+b))*L_ + l;
  size_t r1 = ((size_t)(1*B_+b))*L_ + l1;
  size_t r2 = ((size_t)(2*B_+b))*L_ + (L_-1-l);
  size_t r3 = ((size_t)(3*B_+b))*L_ + (L_-1-l1);
  int lane = threadIdx.x;
  float v[3]; float s = 0.f;
  #pragma unroll
  for (int i=0;i<3;i++){
    int d = lane + i*64;
    float t = hid[r0*D_+d]+res[r0*D_+d] + hid[r1*D_+d]+res[r1*D_+d]
            + hid[r2*D_+d]+res[r2*D_+d] + hid[r3*D_+d]+res[r3*D_+d];
    v[i]=t; s+=t;
  }
  #pragma unroll
  for (int off=32;off;off>>=1) s += __shfl_xor(s,off);
  float m = s*(1.f/D_); float q=0.f;
  #pragma unroll
  for (int i=0;i<3;i++){ float dd=v[i]-m; q+=dd*dd; }
  #pragma unroll
  for (int off=32;off;off>>=1) q += __shfl_xor(q,off);
  float inv = rsqrtf(q*(1.f/D_)+EPS_);
  float v2[3]; s = 0.f;
  #pragma unroll
  for (int i=0;i<3;i++){ int d=lane+i*64; float t=(v[i]-m)*inv*onw[d]+onb[d]; v2[i]=t; s+=t; }
  #pragma unroll
  for (int off=32;off;off>>=1) s += __shfl_xor(s,off);
  float m2 = s*(1.f/D_); q=0.f;
  #pragma unroll
  for (int i=0;i<3;i++){ float dd=v2[i]-m2; q+=dd*dd; }
  #pragma unroll
  for (int off=32;off;off>>=1) q += __shfl_xor(q,off);
  float inv2 = rsqrtf(q*(1.f/D_)+EPS_);
  #pragma unroll
  for (int i=0;i<3;i++){ int d=lane+i*64; ynorm[((size_t)b*L_+l)*D_+d] = (v2[i]-m2)*inv2*hlw[d]+hlb[d]; }
}

// ---------------- mean over L (deterministic, no atomics) -----------------
__global__ __launch_bounds__(192) void k_mean(const float* __restrict__ ynorm, float* __restrict__ ybar)
{
  int b = blockIdx.x, d = threadIdx.x;
  float s = 0.f;
  for (int l = 0; l < L_; ++l) s += ynorm[((size_t)b*L_+l)*D_ + d];
  ybar[b*D_+d] = s * (1.f/L_);
}

// ---------------- classifier head -----------------------------------------
__global__ __launch_bounds__(256) void k_head(
    const float* __restrict__ ybar, const float* __restrict__ hw, const float* __restrict__ hb,
    float* __restrict__ out)
{
  __shared__ float ys[D_];
  int b = blockIdx.x >> 2;
  int c = (blockIdx.x & 3)*256 + threadIdx.x;
  for (int i = threadIdx.x; i < D_; i += 256) ys[i] = ybar[b*D_+i];
  __syncthreads();
  if (c < NCLS_) {
    float acc = hb[c];
    const float* wr = hw + (size_t)c*D_;
    for (int dd = 0; dd < D_; dd += 4) {
      float4 a4 = *reinterpret_cast<const float4*>(&ys[dd]);
      float4 b4 = *reinterpret_cast<const float4*>(&wr[dd]);
      acc += a4.x*b4.x + a4.y*b4.y + a4.z*b4.z + a4.w*b4.w;
    }
    out[(size_t)b*NCLS_ + c] = acc;
  }
}

extern "C" void kernel_launch(void* const* d_in, const int* in_sizes, int n_in,
                              void* d_out, int out_size, void* d_ws, size_t ws_size,
                              hipStream_t stream)
{
  const float* x          = (const float*)d_in[0];
  const float* patch_w    = (const float*)d_in[1];
  const float* patch_b    = (const float*)d_in[2];
  const float* pe_ln_w    = (const float*)d_in[3];
  const float* pe_ln_b    = (const float*)d_in[4];
  const float* ln_w       = (const float*)d_in[5];
  const float* ln_b       = (const float*)d_in[6];
  const float* in_proj_w  = (const float*)d_in[7];
  const float* conv_w     = (const float*)d_in[8];
  const float* conv_b     = (const float*)d_in[9];
  const float* x_proj_w   = (const float*)d_in[10];
  const float* dt_w       = (const float*)d_in[11];
  const float* dt_b       = (const float*)d_in[12];
  const float* A_log      = (const float*)d_in[13];
  const float* Dp         = (const float*)d_in[14];
  const float* out_proj_w = (const float*)d_in[15];
  const float* out_norm_w = (const float*)d_in[16];
  const float* out_norm_b = (const float*)d_in[17];
  const float* head_ln_w  = (const float*)d_in[18];
  const float* head_ln_b  = (const float*)d_in[19];
  const float* head_w     = (const float*)d_in[20];
  const float* head_b     = (const float*)d_in[21];
  float* out = (float*)d_out;

  float* ws = (float*)d_ws;
  float* hidden   = ws;                    // 1,204,224
  float* residual = hidden   + 1204224;    // 1,204,224
  float* xln      = residual + 1204224;    // 1,204,224
  float* xz       = xln      + 1204224;    // 4,816,896
  float* u        = xz       + 4816896;    // 2,408,448
  float* xdbl     = u        + 2408448;    //   275,968
  float* delta    = xdbl     + 275968;     // 2,408,448
  float* yg       = delta    + 2408448;    // 2,408,448
  float* ynorm    = yg       + 2408448;    //   301,056
  float* ybar     = ynorm    + 301056;     //     1,536

  k_patch<<<B_*L_, 256, 0, stream>>>(x, patch_w, patch_b, pe_ln_w, pe_ln_b, hidden, residual);

  for (int layer = 0; layer < DEPTH_; ++layer) {
    k_ln_res<<<M_TOTAL/4, 256, 0, stream>>>(ln_w, ln_b, hidden, residual, xln, layer);
    k_gemm<<<dim3(M_TOTAL/32, 768/64), 256, 0, stream>>>(
        xln, in_proj_w + (size_t)layer*768*D_, xz, 768, D_, DEPTH_*768*D_);
    k_conv<<<(M_TOTAL*DIN+255)/256, 256, 0, stream>>>(xz, conv_w, conv_b, u, layer);
    k_xproj<<<M_TOTAL, 64, 0, stream>>>(u, x_proj_w, xdbl, layer);
    k_delta<<<(M_TOTAL*DIN+255)/256, 256, 0, stream>>>(xdbl, dt_w, dt_b, delta, layer);
    k_scan<<<4*B_*24, 256, 0, stream>>>(delta, u, xdbl, xz, A_log, Dp, yg, layer);
    k_gemm<<<dim3(M_TOTAL/32, D_/64), 256, 0, stream>>>(
        yg, out_proj_w + (size_t)layer*D_*DIN, hidden, D_, DIN, DEPTH_*D_*DIN);
  }

  k_combine<<<B_*L_, 64, 0, stream>>>(hidden, residual, out_norm_w, out_norm_b,
                                      head_ln_w, head_ln_b, ynorm);
  k_mean<<<B_, 192, 0, stream>>>(ynorm, ybar);
  k_head<<<B_*4, 256, 0, stream>>>(ybar, head_w, head_b, out);
}

// Round 3
// 1419.657 us; speedup vs baseline: 1.8257x; 1.3112x over previous
//
#include <hip/hip_runtime.h>

#define B_ 8
#define IMGSZ 224
#define PATCH 16
#define D_ 192
#define DEPTH_ 8
#define H_ 14
#define W_ 14
#define L_ 196
#define DIN 384
#define DSTATE 16
#define DCONV 4
#define DTR 12
#define NCLS_ 1000
#define EPS_ 1e-5f
#define ROWS_PER_DIR (B_*L_)      /* 1568 */
#define M_TOTAL (4*ROWS_PER_DIR)  /* 6272 */

typedef unsigned short ushort_t;
typedef unsigned int uint_t;
typedef __attribute__((ext_vector_type(8)))  short bf16x8;
typedef __attribute__((ext_vector_type(16))) float f32x16;

__device__ __forceinline__ ushort_t f2bf(float f) {
  uint_t u = __builtin_bit_cast(uint_t, f);
  u += 0x7fffu + ((u >> 16) & 1u);          // RNE
  return (ushort_t)(u >> 16);
}

// ---------------- f32 -> bf16 weight conversion (4 elems/thread) ----------
__global__ __launch_bounds__(256) void k_cvt(const float* __restrict__ src,
                                             ushort_t* __restrict__ dst, int n4)
{
  int i = blockIdx.x*256 + threadIdx.x;
  if (i >= n4) return;
  float4 v = reinterpret_cast<const float4*>(src)[i];
  ushort4 o;
  o.x = f2bf(v.x); o.y = f2bf(v.y); o.z = f2bf(v.z); o.w = f2bf(v.w);
  reinterpret_cast<ushort4*>(dst)[i] = o;
}

// ---------------- im2col of 16x16 patches -> bf16 [1568][768] -------------
__global__ __launch_bounds__(256) void k_im2col(const float* __restrict__ x,
                                                ushort_t* __restrict__ Xp)
{
  int idx = blockIdx.x*256 + threadIdx.x;
  if (idx >= ROWS_PER_DIR*768) return;
  int row = idx / 768, k = idx - row*768;
  int b = row / L_, l = row - b*L_;
  int hh = l / W_, ww = l - hh*W_;
  int c = k >> 8, rem = k & 255, pi = rem >> 4, pj = rem & 15;
  float v = x[(((size_t)b*3 + c)*IMGSZ + hh*PATCH + pi)*IMGSZ + ww*PATCH + pj];
  Xp[idx] = f2bf(v);
}

// ---------------- MFMA bf16 GEMM: C[M,N] = X[M,K] * W[N,K]^T (f32 out) ----
// one wave per 32x32 tile; A/B fragments straight from global (L2-resident)
template<int KT>
__global__ __launch_bounds__(64) void k_gemm_mfma(
    const ushort_t* __restrict__ X, const ushort_t* __restrict__ W,
    float* __restrict__ C, int N, int wstride, int rows_per_dir)
{
  int row0 = blockIdx.x*32, col0 = blockIdx.y*32;
  int dir = row0 / rows_per_dir;
  const ushort_t* Wp = W + (size_t)dir*wstride;
  int l = threadIdx.x;
  int r31 = l & 31, khalf = (l >> 5)*8;
  const ushort_t* aptr = X  + (size_t)(row0 + r31)*KT + khalf;
  const ushort_t* bptr = Wp + (size_t)(col0 + r31)*KT + khalf;
  f32x16 acc0 = {}; f32x16 acc1 = {};
  #pragma unroll
  for (int k = 0; k < KT; k += 32) {
    bf16x8 a0 = *reinterpret_cast<const bf16x8*>(aptr + k);
    bf16x8 b0 = *reinterpret_cast<const bf16x8*>(bptr + k);
    bf16x8 a1 = *reinterpret_cast<const bf16x8*>(aptr + k + 16);
    bf16x8 b1 = *reinterpret_cast<const bf16x8*>(bptr + k + 16);
    acc0 = __builtin_amdgcn_mfma_f32_32x32x16_bf16(a0, b0, acc0, 0, 0, 0);
    acc1 = __builtin_amdgcn_mfma_f32_32x32x16_bf16(a1, b1, acc1, 0, 0, 0);
  }
  #pragma unroll
  for (int r = 0; r < 16; ++r) {
    int row = (r & 3) + 8*(r >> 2) + 4*(l >> 5);
    C[(size_t)(row0 + row)*N + col0 + r31] = acc0[r] + acc1[r];
  }
}

// ---------------- patch LN + scatter into 4 directional seqs --------------
__global__ __launch_bounds__(64) void k_peln(
    const float* __restrict__ Cp, const float* __restrict__ pb,
    const float* __restrict__ plw, const float* __restrict__ plb,
    float* __restrict__ hidden, float* __restrict__ residual)
{
  int blk = blockIdx.x;            // b*L + l
  int b = blk / L_, l = blk - b*L_;
  int hh = l / W_, ww = l - hh*W_;
  int lane = threadIdx.x;
  float v[3]; float s = 0.f;
  #pragma unroll
  for (int i = 0; i < 3; ++i) {
    int d = lane + i*64;
    float t = Cp[(size_t)blk*D_ + d] + pb[d];
    v[i] = t; s += t;
  }
  #pragma unroll
  for (int off = 32; off; off >>= 1) s += __shfl_xor(s, off);
  float m = s*(1.f/D_); float q = 0.f;
  #pragma unroll
  for (int i = 0; i < 3; ++i) { float dd = v[i]-m; q += dd*dd; }
  #pragma unroll
  for (int off = 32; off; off >>= 1) q += __shfl_xor(q, off);
  float inv = rsqrtf(q*(1.f/D_)+EPS_);
  int l1 = ww*W_ + hh;
  size_t r0 = ((size_t)(0*B_+b))*L_ + l;
  size_t r1 = ((size_t)(1*B_+b))*L_ + l1;
  size_t r2 = ((size_t)(2*B_+b))*L_ + (L_-1-l);
  size_t r3 = ((size_t)(3*B_+b))*L_ + (L_-1-l1);
  #pragma unroll
  for (int i = 0; i < 3; ++i) {
    int d = lane + i*64;
    float nv = (v[i]-m)*inv*plw[d] + plb[d];
    hidden[r0*D_+d]=nv; hidden[r1*D_+d]=nv; hidden[r2*D_+d]=nv; hidden[r3*D_+d]=nv;
    residual[r0*D_+d]=0.f; residual[r1*D_+d]=0.f; residual[r2*D_+d]=0.f; residual[r3*D_+d]=0.f;
  }
}

// ---------------- residual += hidden; xln = bf16(LN(residual)*w+b) --------
__global__ __launch_bounds__(256) void k_ln_res(
    const float* __restrict__ lnw, const float* __restrict__ lnb,
    const float* __restrict__ hidden, float* __restrict__ residual,
    ushort_t* __restrict__ xln, int layer)
{
  int row = blockIdx.x*4 + (threadIdx.x >> 6);
  int lane = threadIdx.x & 63;
  int kdir = row / ROWS_PER_DIR;
  const float* w  = lnw + (size_t)(kdir*DEPTH_+layer)*D_;
  const float* bb = lnb + (size_t)(kdir*DEPTH_+layer)*D_;
  size_t base = (size_t)row*D_;
  float v[3]; float s = 0.f;
  #pragma unroll
  for (int i=0;i<3;i++){
    int d = lane + i*64;
    float t = residual[base+d] + hidden[base+d];
    residual[base+d] = t;
    v[i] = t; s += t;
  }
  #pragma unroll
  for (int off=32;off;off>>=1) s += __shfl_xor(s,off);
  float m = s*(1.f/D_);
  float q = 0.f;
  #pragma unroll
  for (int i=0;i<3;i++){ float dd = v[i]-m; q += dd*dd; }
  #pragma unroll
  for (int off=32;off;off>>=1) q += __shfl_xor(q,off);
  float inv = rsqrtf(q*(1.f/D_)+EPS_);
  #pragma unroll
  for (int i=0;i<3;i++){ int d = lane+i*64; xln[base+d] = f2bf((v[i]-m)*inv*w[d]+bb[d]); }
}

// ---------------- causal depthwise conv (k=4) + bias + SiLU ---------------
__global__ __launch_bounds__(256) void k_conv(
    const float* __restrict__ xz, const float* __restrict__ cw, const float* __restrict__ cb,
    float* __restrict__ u, int layer)
{
  int idx = blockIdx.x*256 + threadIdx.x;
  if (idx >= M_TOTAL*DIN) return;
  int row = idx / DIN, d = idx - row*DIN;
  int kdir = row / ROWS_PER_DIR;
  int l = row % L_;
  const float* cwp = cw + ((size_t)(kdir*DEPTH_+layer)*DIN + d)*DCONV;
  float acc = cb[(size_t)(kdir*DEPTH_+layer)*DIN + d];
  #pragma unroll
  for (int t = 0; t < DCONV; ++t) {
    int ll = l - 3 + t;
    if (ll >= 0) acc += xz[((size_t)row + (ll - l))*768 + d] * cwp[t];
  }
  u[idx] = acc / (1.f + expf(-acc));   // SiLU
}

// ---------------- x_proj: xdbl[row,0:44] = u_row @ x_proj_w^T -------------
__global__ __launch_bounds__(64) void k_xproj(
    const float* __restrict__ u, const float* __restrict__ xw,
    float* __restrict__ xdbl, int layer)
{
  int row = blockIdx.x;
  int kdir = row / ROWS_PER_DIR;
  __shared__ float us[DIN];
  int lane = threadIdx.x;
  for (int i = lane; i < DIN; i += 64) us[i] = u[(size_t)row*DIN + i];
  __syncthreads();
  if (lane < 44) {
    const float* wr = xw + ((size_t)(kdir*DEPTH_+layer)*44 + lane)*DIN;
    float acc = 0.f;
    for (int dd = 0; dd < DIN; dd += 4) {
      float4 a4 = *reinterpret_cast<const float4*>(&us[dd]);
      float4 b4 = *reinterpret_cast<const float4*>(&wr[dd]);
      acc += a4.x*b4.x + a4.y*b4.y + a4.z*b4.z + a4.w*b4.w;
    }
    xdbl[(size_t)row*44 + lane] = acc;
  }
}

// ---------------- delta = softplus(dt @ dt_w^T + dt_b) --------------------
__global__ __launch_bounds__(256) void k_delta(
    const float* __restrict__ xdbl, const float* __restrict__ dtw, const float* __restrict__ dtb,
    float* __restrict__ delta, int layer)
{
  int idx = blockIdx.x*256 + threadIdx.x;
  if (idx >= M_TOTAL*DIN) return;
  int row = idx / DIN, d = idx - row*DIN;
  int kdir = row / ROWS_PER_DIR;
  const float* xr = xdbl + (size_t)row*44;
  const float* wr = dtw + ((size_t)(kdir*DEPTH_+layer)*DIN + d)*DTR;
  float acc = dtb[(size_t)(kdir*DEPTH_+layer)*DIN + d];
  #pragma unroll
  for (int j = 0; j < DTR; ++j) acc += xr[j]*wr[j];
  delta[idx] = (acc > 20.f) ? acc : log1pf(expf(acc));
}

// ---------------- selective scan + skip(D) + SiLU(z) gate -----------------
#define SCHUNK 14
#define NCHUNK 14
__global__ __launch_bounds__(256) void k_scan(
    const float* __restrict__ delta, const float* __restrict__ u,
    const float* __restrict__ xdbl, const float* __restrict__ xz,
    const float* __restrict__ Alog, const float* __restrict__ Dp,
    ushort_t* __restrict__ yg, int layer)
{
  int blk = blockIdx.x;
  int kdir = blk / (B_*24);
  int rem = blk % (B_*24);
  int b = rem / 24, dc = rem % 24;
  int tid = threadIdx.x;
  int lane16 = tid & 15, dloc = tid >> 4;
  int d = dc*16 + dloc;
  size_t pl = (size_t)(kdir*DEPTH_+layer)*DIN + d;
  float a = -expf(Alog[pl*DSTATE + lane16]);
  float Dv = Dp[pl];
  size_t rowbase = ((size_t)kdir*B_ + b)*L_;

  __shared__ float sd[SCHUNK][16], su[SCHUNK][16], sB[SCHUNK][16],
                   sC[SCHUNK][16], sz[SCHUNK][16], sy[SCHUNK][16];

  int ll = tid >> 4;      // 0..13 valid when tid < 224
  int cc = tid & 15;
  bool ldr = tid < 224;

  float rd = 0.f, ru = 0.f, rB = 0.f, rC = 0.f, rz = 0.f;
  if (ldr) {
    size_t r = rowbase + ll;
    rd = delta[r*DIN + dc*16 + cc];
    ru = u[r*DIN + dc*16 + cc];
    rB = xdbl[r*44 + DTR + cc];
    rC = xdbl[r*44 + DTR + DSTATE + cc];
    rz = xz[r*768 + DIN + dc*16 + cc];
  }

  float h = 0.f;
  for (int ch = 0; ch < NCHUNK; ++ch) {
    if (ldr) { sd[ll][cc]=rd; su[ll][cc]=ru; sB[ll][cc]=rB; sC[ll][cc]=rC; sz[ll][cc]=rz; }
    __syncthreads();
    if (ch+1 < NCHUNK && ldr) {
      size_t r = rowbase + (ch+1)*SCHUNK + ll;
      rd = delta[r*DIN + dc*16 + cc];
      ru = u[r*DIN + dc*16 + cc];
      rB = xdbl[r*44 + DTR + cc];
      rC = xdbl[r*44 + DTR + DSTATE + cc];
      rz = xz[r*768 + DIN + dc*16 + cc];
    }
    #pragma unroll
    for (int l = 0; l < SCHUNK; ++l) {
      float dl = sd[l][dloc];
      float ul = su[l][dloc];
      float Bv = sB[l][lane16];
      float Cv = sC[l][lane16];
      h = h*__expf(dl*a) + dl*ul*Bv;
      float p = h*Cv;
      p += __shfl_xor(p, 1, 16);
      p += __shfl_xor(p, 2, 16);
      p += __shfl_xor(p, 4, 16);
      p += __shfl_xor(p, 8, 16);
      if (lane16 == 0) {
        float z = sz[l][dloc];
        sy[l][dloc] = (p + ul*Dv) * (z / (1.f + __expf(-z)));
      }
    }
    __syncthreads();
    if (ldr) yg[(rowbase + ch*SCHUNK + ll)*DIN + dc*16 + cc] = f2bf(sy[ll][cc]);
    __syncthreads();
  }
}

// ---------------- merge 4 directions + out_norm LN + head LN --------------
__global__ __launch_bounds__(64) void k_combine(
    const float* __restrict__ hid, const float* __restrict__ res,
    const float* __restrict__ onw, const float* __restrict__ onb,
    const float* __restrict__ hlw, const float* __restrict__ hlb,
    float* __restrict__ ynorm)
{
  int blk = blockIdx.x;
  int b = blk / L_, l = blk % L_;
  int hh = l / W_, ww = l % W_;
  int l1 = ww*W_ + hh;
  size_t r0 = ((size_t)(0*B_+b))*L_ + l;
  size_t r1 = ((size_t)(1*B_+b))*L_ + l1;
  size_t r2 = ((size_t)(2*B_+b))*L_ + (L_-1-l);
  size_t r3 = ((size_t)(3*B_+b))*L_ + (L_-1-l1);
  int lane = threadIdx.x;
  float v[3]; float s = 0.f;
  #pragma unroll
  for (int i=0;i<3;i++){
    int d = lane + i*64;
    float t = hid[r0*D_+d]+res[r0*D_+d] + hid[r1*D_+d]+res[r1*D_+d]
            + hid[r2*D_+d]+res[r2*D_+d] + hid[r3*D_+d]+res[r3*D_+d];
    v[i]=t; s+=t;
  }
  #pragma unroll
  for (int off=32;off;off>>=1) s += __shfl_xor(s,off);
  float m = s*(1.f/D_); float q=0.f;
  #pragma unroll
  for (int i=0;i<3;i++){ float dd=v[i]-m; q+=dd*dd; }
  #pragma unroll
  for (int off=32;off;off>>=1) q += __shfl_xor(q,off);
  float inv = rsqrtf(q*(1.f/D_)+EPS_);
  float v2[3]; s = 0.f;
  #pragma unroll
  for (int i=0;i<3;i++){ int d=lane+i*64; float t=(v[i]-m)*inv*onw[d]+onb[d]; v2[i]=t; s+=t; }
  #pragma unroll
  for (int off=32;off;off>>=1) s += __shfl_xor(s,off);
  float m2 = s*(1.f/D_); q=0.f;
  #pragma unroll
  for (int i=0;i<3;i++){ float dd=v2[i]-m2; q+=dd*dd; }
  #pragma unroll
  for (int off=32;off;off>>=1) q += __shfl_xor(q,off);
  float inv2 = rsqrtf(q*(1.f/D_)+EPS_);
  #pragma unroll
  for (int i=0;i<3;i++){ int d=lane+i*64; ynorm[((size_t)b*L_+l)*D_+d] = (v2[i]-m2)*inv2*hlw[d]+hlb[d]; }
}

// ---------------- mean over L ---------------------------------------------
__global__ __launch_bounds__(192) void k_mean(const float* __restrict__ ynorm, float* __restrict__ ybar)
{
  int b = blockIdx.x, d = threadIdx.x;
  float s = 0.f;
  for (int l = 0; l < L_; ++l) s += ynorm[((size_t)b*L_+l)*D_ + d];
  ybar[b*D_+d] = s * (1.f/L_);
}

// ---------------- classifier head -----------------------------------------
__global__ __launch_bounds__(256) void k_head(
    const float* __restrict__ ybar, const float* __restrict__ hw, const float* __restrict__ hb,
    float* __restrict__ out)
{
  __shared__ float ys[D_];
  int b = blockIdx.x >> 2;
  int c = (blockIdx.x & 3)*256 + threadIdx.x;
  for (int i = threadIdx.x; i < D_; i += 256) ys[i] = ybar[b*D_+i];
  __syncthreads();
  if (c < NCLS_) {
    float acc = hb[c];
    const float* wr = hw + (size_t)c*D_;
    for (int dd = 0; dd < D_; dd += 4) {
      float4 a4 = *reinterpret_cast<const float4*>(&ys[dd]);
      float4 b4 = *reinterpret_cast<const float4*>(&wr[dd]);
      acc += a4.x*b4.x + a4.y*b4.y + a4.z*b4.z + a4.w*b4.w;
    }
    out[(size_t)b*NCLS_ + c] = acc;
  }
}

extern "C" void kernel_launch(void* const* d_in, const int* in_sizes, int n_in,
                              void* d_out, int out_size, void* d_ws, size_t ws_size,
                              hipStream_t stream)
{
  const float* x          = (const float*)d_in[0];
  const float* patch_w    = (const float*)d_in[1];
  const float* patch_b    = (const float*)d_in[2];
  const float* pe_ln_w    = (const float*)d_in[3];
  const float* pe_ln_b    = (const float*)d_in[4];
  const float* ln_w       = (const float*)d_in[5];
  const float* ln_b       = (const float*)d_in[6];
  const float* in_proj_w  = (const float*)d_in[7];
  const float* conv_w     = (const float*)d_in[8];
  const float* conv_b     = (const float*)d_in[9];
  const float* x_proj_w   = (const float*)d_in[10];
  const float* dt_w       = (const float*)d_in[11];
  const float* dt_b       = (const float*)d_in[12];
  const float* A_log      = (const float*)d_in[13];
  const float* Dp         = (const float*)d_in[14];
  const float* out_proj_w = (const float*)d_in[15];
  const float* out_norm_w = (const float*)d_in[16];
  const float* out_norm_b = (const float*)d_in[17];
  const float* head_ln_w  = (const float*)d_in[18];
  const float* head_ln_b  = (const float*)d_in[19];
  const float* head_w     = (const float*)d_in[20];
  const float* head_b     = (const float*)d_in[21];
  float* out = (float*)d_out;

  float* ws = (float*)d_ws;
  float*   hidden   = ws;                         // 1,204,224 f32
  float*   residual = hidden   + 1204224;         // 1,204,224 f32
  float*   xz       = residual + 1204224;         // 4,816,896 f32
  float*   u        = xz       + 4816896;         // 2,408,448 f32
  float*   xdbl     = u        + 2408448;         //   275,968 f32
  float*   delta    = xdbl     + 275968;          // 2,408,448 f32
  ushort_t* yg_bf   = (ushort_t*)(delta + 2408448);   // 2,408,448 ush (1,204,224 slots)
  ushort_t* xln_bf  = (ushort_t*)((float*)yg_bf + 1204224); // 1,204,224 ush (602,112 slots)
  ushort_t* wbf     = (ushort_t*)((float*)xln_bf + 602112); // 7,225,344 ush (3,612,672 slots)
  ushort_t* pw_bf   = wbf;                        //   147,456
  ushort_t* inw_bf  = wbf + 147456;               // 4,718,592
  ushort_t* outw_bf = inw_bf + 4718592;           // 2,359,296
  // patch-phase aliases inside xz (xz not yet written):
  ushort_t* Xp      = (ushort_t*)xz;              // 1,204,224 ush
  float*   C_patch  = xz + 602112;                //   301,056 f32
  // tail aliases inside delta (delta dead after last scan):
  float*   ynorm    = delta;                      //   301,056 f32
  float*   ybar     = delta + 301056;             //     1,536 f32

  // one-time (per call) weight conversions
  k_cvt<<<(147456/4+255)/256, 256, 0, stream>>>(patch_w, pw_bf, 147456/4);
  k_cvt<<<(4718592/4+255)/256, 256, 0, stream>>>(in_proj_w, inw_bf, 4718592/4);
  k_cvt<<<(2359296/4+255)/256, 256, 0, stream>>>(out_proj_w, outw_bf, 2359296/4);

  // patch embed: im2col -> mfma gemm -> LN + scatter
  k_im2col<<<(ROWS_PER_DIR*768+255)/256, 256, 0, stream>>>(x, Xp);
  k_gemm_mfma<768><<<dim3(ROWS_PER_DIR/32, D_/32), 64, 0, stream>>>(
      Xp, pw_bf, C_patch, D_, 0, ROWS_PER_DIR);
  k_peln<<<ROWS_PER_DIR, 64, 0, stream>>>(C_patch, patch_b, pe_ln_w, pe_ln_b, hidden, residual);

  for (int layer = 0; layer < DEPTH_; ++layer) {
    k_ln_res<<<M_TOTAL/4, 256, 0, stream>>>(ln_w, ln_b, hidden, residual, xln_bf, layer);
    k_gemm_mfma<192><<<dim3(M_TOTAL/32, 768/32), 64, 0, stream>>>(
        xln_bf, inw_bf + (size_t)layer*768*D_, xz, 768, DEPTH_*768*D_, ROWS_PER_DIR);
    k_conv<<<(M_TOTAL*DIN+255)/256, 256, 0, stream>>>(xz, conv_w, conv_b, u, layer);
    k_xproj<<<M_TOTAL, 64, 0, stream>>>(u, x_proj_w, xdbl, layer);
    k_delta<<<(M_TOTAL*DIN+255)/256, 256, 0, stream>>>(xdbl, dt_w, dt_b, delta, layer);
    k_scan<<<4*B_*24, 256, 0, stream>>>(delta, u, xdbl, xz, A_log, Dp, yg_bf, layer);
    k_gemm_mfma<384><<<dim3(M_TOTAL/32, D_/32), 64, 0, stream>>>(
        yg_bf, outw_bf + (size_t)layer*D_*DIN, hidden, D_, DEPTH_*D_*DIN, ROWS_PER_DIR);
  }

  k_combine<<<B_*L_, 64, 0, stream>>>(hidden, residual, out_norm_w, out_norm_b,
                                      head_ln_w, head_ln_b, ynorm);
  k_mean<<<B_, 192, 0, stream>>>(ynorm, ybar);
  k_head<<<B_*4, 256, 0, stream>>>(ybar, head_w, head_b, out);
}

// Round 4
// 728.519 us; speedup vs baseline: 3.5577x; 1.9487x over previous
//
#include <hip/hip_runtime.h>

#define B_ 8
#define IMGSZ 224
#define PATCH 16
#define D_ 192
#define DEPTH_ 8
#define H_ 14
#define W_ 14
#define L_ 196
#define DIN 384
#define DSTATE 16
#define DCONV 4
#define DTR 12
#define NCLS_ 1000
#define EPS_ 1e-5f
#define ROWS_PER_DIR (B_*L_)      /* 1568 */
#define M_TOTAL (4*ROWS_PER_DIR)  /* 6272 */

typedef unsigned short ushort_t;
typedef unsigned int uint_t;
typedef __attribute__((ext_vector_type(8)))  short bf16x8;
typedef __attribute__((ext_vector_type(16))) float f32x16;

__device__ __forceinline__ ushort_t f2bf(float f) {
  uint_t u = __builtin_bit_cast(uint_t, f);
  u += 0x7fffu + ((u >> 16) & 1u);          // RNE
  return (ushort_t)(u >> 16);
}

// ---------------- f32 -> bf16 weight conversion (4 elems/thread) ----------
__global__ __launch_bounds__(256) void k_cvt(const float* __restrict__ src,
                                             ushort_t* __restrict__ dst, int n4)
{
  int i = blockIdx.x*256 + threadIdx.x;
  if (i >= n4) return;
  float4 v = reinterpret_cast<const float4*>(src)[i];
  ushort4 o;
  o.x = f2bf(v.x); o.y = f2bf(v.y); o.z = f2bf(v.z); o.w = f2bf(v.w);
  reinterpret_cast<ushort4*>(dst)[i] = o;
}

// ---------------- x_proj_w [32][44][384] -> padded bf16 [32][64][384] -----
__global__ __launch_bounds__(256) void k_cvt_xw(const float* __restrict__ src,
                                                ushort_t* __restrict__ dst)
{
  int idx = blockIdx.x*256 + threadIdx.x;
  if (idx >= 32*64*384) return;
  int g = idx / (64*384);
  int r = (idx / 384) % 64;
  int k = idx % 384;
  float v = (r < 44) ? src[((size_t)g*44 + r)*384 + k] : 0.f;
  dst[idx] = f2bf(v);
}

// ---------------- im2col of 16x16 patches -> bf16 [1568][768] -------------
__global__ __launch_bounds__(256) void k_im2col(const float* __restrict__ x,
                                                ushort_t* __restrict__ Xp)
{
  int idx = blockIdx.x*256 + threadIdx.x;
  if (idx >= ROWS_PER_DIR*768) return;
  int row = idx / 768, k = idx - row*768;
  int b = row / L_, l = row - b*L_;
  int hh = l / W_, ww = l - hh*W_;
  int c = k >> 8, rem = k & 255, pi = rem >> 4, pj = rem & 15;
  float v = x[(((size_t)b*3 + c)*IMGSZ + hh*PATCH + pi)*IMGSZ + ww*PATCH + pj];
  Xp[idx] = f2bf(v);
}

// ---------------- MFMA bf16 GEMM: C[M,N] = X[M,K] * W[N,K]^T (f32 out) ----
// one wave per 32x32 tile; nb = column store bound (output stride N)
template<int KT>
__global__ __launch_bounds__(64) void k_gemm_mfma(
    const ushort_t* __restrict__ X, const ushort_t* __restrict__ W,
    float* __restrict__ C, int N, int nb, int wstride, int rows_per_dir)
{
  int row0 = blockIdx.x*32, col0 = blockIdx.y*32;
  int dir = row0 / rows_per_dir;
  const ushort_t* Wp = W + (size_t)dir*wstride;
  int l = threadIdx.x;
  int r31 = l & 31, khalf = (l >> 5)*8;
  const ushort_t* aptr = X  + (size_t)(row0 + r31)*KT + khalf;
  const ushort_t* bptr = Wp + (size_t)(col0 + r31)*KT + khalf;
  f32x16 acc0 = {}; f32x16 acc1 = {};
  #pragma unroll
  for (int k = 0; k < KT; k += 32) {
    bf16x8 a0 = *reinterpret_cast<const bf16x8*>(aptr + k);
    bf16x8 b0 = *reinterpret_cast<const bf16x8*>(bptr + k);
    bf16x8 a1 = *reinterpret_cast<const bf16x8*>(aptr + k + 16);
    bf16x8 b1 = *reinterpret_cast<const bf16x8*>(bptr + k + 16);
    acc0 = __builtin_amdgcn_mfma_f32_32x32x16_bf16(a0, b0, acc0, 0, 0, 0);
    acc1 = __builtin_amdgcn_mfma_f32_32x32x16_bf16(a1, b1, acc1, 0, 0, 0);
  }
  int col = col0 + r31;
  if (col < nb) {
    #pragma unroll
    for (int r = 0; r < 16; ++r) {
      int row = (r & 3) + 8*(r >> 2) + 4*(l >> 5);
      C[(size_t)(row0 + row)*N + col] = acc0[r] + acc1[r];
    }
  }
}

// ---------------- patch LN + scatter into 4 directional seqs --------------
__global__ __launch_bounds__(64) void k_peln(
    const float* __restrict__ Cp, const float* __restrict__ pb,
    const float* __restrict__ plw, const float* __restrict__ plb,
    float* __restrict__ hidden, float* __restrict__ residual)
{
  int blk = blockIdx.x;            // b*L + l
  int b = blk / L_, l = blk - b*L_;
  int hh = l / W_, ww = l - hh*W_;
  int lane = threadIdx.x;
  float v[3]; float s = 0.f;
  #pragma unroll
  for (int i = 0; i < 3; ++i) {
    int d = lane + i*64;
    float t = Cp[(size_t)blk*D_ + d] + pb[d];
    v[i] = t; s += t;
  }
  #pragma unroll
  for (int off = 32; off; off >>= 1) s += __shfl_xor(s, off);
  float m = s*(1.f/D_); float q = 0.f;
  #pragma unroll
  for (int i = 0; i < 3; ++i) { float dd = v[i]-m; q += dd*dd; }
  #pragma unroll
  for (int off = 32; off; off >>= 1) q += __shfl_xor(q, off);
  float inv = rsqrtf(q*(1.f/D_)+EPS_);
  int l1 = ww*W_ + hh;
  size_t r0 = ((size_t)(0*B_+b))*L_ + l;
  size_t r1 = ((size_t)(1*B_+b))*L_ + l1;
  size_t r2 = ((size_t)(2*B_+b))*L_ + (L_-1-l);
  size_t r3 = ((size_t)(3*B_+b))*L_ + (L_-1-l1);
  #pragma unroll
  for (int i = 0; i < 3; ++i) {
    int d = lane + i*64;
    float nv = (v[i]-m)*inv*plw[d] + plb[d];
    hidden[r0*D_+d]=nv; hidden[r1*D_+d]=nv; hidden[r2*D_+d]=nv; hidden[r3*D_+d]=nv;
    residual[r0*D_+d]=0.f; residual[r1*D_+d]=0.f; residual[r2*D_+d]=0.f; residual[r3*D_+d]=0.f;
  }
}

// ---------------- residual += hidden; xln = bf16(LN(residual)*w+b) --------
__global__ __launch_bounds__(256) void k_ln_res(
    const float* __restrict__ lnw, const float* __restrict__ lnb,
    const float* __restrict__ hidden, float* __restrict__ residual,
    ushort_t* __restrict__ xln, int layer)
{
  int row = blockIdx.x*4 + (threadIdx.x >> 6);
  int lane = threadIdx.x & 63;
  int kdir = row / ROWS_PER_DIR;
  const float* w  = lnw + (size_t)(kdir*DEPTH_+layer)*D_;
  const float* bb = lnb + (size_t)(kdir*DEPTH_+layer)*D_;
  size_t base = (size_t)row*D_;
  float v[3]; float s = 0.f;
  #pragma unroll
  for (int i=0;i<3;i++){
    int d = lane + i*64;
    float t = residual[base+d] + hidden[base+d];
    residual[base+d] = t;
    v[i] = t; s += t;
  }
  #pragma unroll
  for (int off=32;off;off>>=1) s += __shfl_xor(s,off);
  float m = s*(1.f/D_);
  float q = 0.f;
  #pragma unroll
  for (int i=0;i<3;i++){ float dd = v[i]-m; q += dd*dd; }
  #pragma unroll
  for (int off=32;off;off>>=1) q += __shfl_xor(q,off);
  float inv = rsqrtf(q*(1.f/D_)+EPS_);
  #pragma unroll
  for (int i=0;i<3;i++){ int d = lane+i*64; xln[base+d] = f2bf((v[i]-m)*inv*w[d]+bb[d]); }
}

// ---------------- causal depthwise conv (k=4) + bias + SiLU, float4 -------
// writes f32 u (for scan) and bf16 u (for x_proj MFMA GEMM)
__global__ __launch_bounds__(256) void k_conv(
    const float* __restrict__ xz, const float* __restrict__ cw, const float* __restrict__ cb,
    float* __restrict__ u, ushort_t* __restrict__ ub, int layer)
{
  int idx = blockIdx.x*256 + threadIdx.x;
  if (idx >= M_TOTAL*96) return;
  int row = idx / 96, d4 = (idx - row*96)*4;
  int kdir = row / ROWS_PER_DIR;
  int l = row % L_;
  size_t pbase = (size_t)(kdir*DEPTH_+layer)*DIN + d4;
  const float* cwp = cw + pbase*DCONV;        // 16 consecutive floats
  float wv[16];
  #pragma unroll
  for (int i = 0; i < 4; ++i)
    ((float4*)wv)[i] = ((const float4*)cwp)[i];
  float4 bias = *reinterpret_cast<const float4*>(&cb[pbase]);
  float acc[4] = {bias.x, bias.y, bias.z, bias.w};
  #pragma unroll
  for (int t = 0; t < DCONV; ++t) {
    int ll = l - 3 + t;
    if (ll >= 0) {
      float4 xv = *reinterpret_cast<const float4*>(&xz[((size_t)row + (ll - l))*768 + d4]);
      acc[0] += xv.x * wv[0*4 + t];
      acc[1] += xv.y * wv[1*4 + t];
      acc[2] += xv.z * wv[2*4 + t];
      acc[3] += xv.w * wv[3*4 + t];
    }
  }
  float4 o; ushort4 ob;
  o.x = acc[0] / (1.f + __expf(-acc[0]));
  o.y = acc[1] / (1.f + __expf(-acc[1]));
  o.z = acc[2] / (1.f + __expf(-acc[2]));
  o.w = acc[3] / (1.f + __expf(-acc[3]));
  ob.x = f2bf(o.x); ob.y = f2bf(o.y); ob.z = f2bf(o.z); ob.w = f2bf(o.w);
  *reinterpret_cast<float4*>(&u[(size_t)row*DIN + d4]) = o;
  *reinterpret_cast<ushort4*>(&ub[(size_t)row*DIN + d4]) = ob;
}

// ---------------- delta = softplus(dt @ dt_w^T + dt_b), 4 ch/thread -------
__global__ __launch_bounds__(256) void k_delta(
    const float* __restrict__ xdbl, const float* __restrict__ dtw, const float* __restrict__ dtb,
    float* __restrict__ delta, int layer)
{
  int idx = blockIdx.x*256 + threadIdx.x;
  if (idx >= M_TOTAL*96) return;
  int row = idx / 96, dq = idx - row*96;
  int kdir = row / ROWS_PER_DIR;
  const float* xr = xdbl + (size_t)row*44;
  size_t pbase = (size_t)(kdir*DEPTH_+layer)*DIN + dq*4;
  const float* wr = dtw + pbase*DTR;          // 48 consecutive floats
  float4 bias = *reinterpret_cast<const float4*>(&dtb[pbase]);
  float acc[4] = {bias.x, bias.y, bias.z, bias.w};
  float xv[12];
  #pragma unroll
  for (int i = 0; i < 3; ++i) ((float4*)xv)[i] = ((const float4*)xr)[i];
  #pragma unroll
  for (int j = 0; j < 4; ++j) {
    #pragma unroll
    for (int t = 0; t < DTR; ++t) acc[j] += xv[t]*wr[j*DTR + t];
  }
  float4 o;
  o.x = (acc[0] > 20.f) ? acc[0] : log1pf(__expf(acc[0]));
  o.y = (acc[1] > 20.f) ? acc[1] : log1pf(__expf(acc[1]));
  o.z = (acc[2] > 20.f) ? acc[2] : log1pf(__expf(acc[2]));
  o.w = (acc[3] > 20.f) ? acc[3] : log1pf(__expf(acc[3]));
  *reinterpret_cast<float4*>(&delta[(size_t)row*DIN + dq*4]) = o;
}

// ---------------- selective scan + skip(D) + SiLU(z) gate -----------------
// block: 16 channels x 16 states; grid: 4*8*24.  Chunked, shuffle-free:
// phase1: bulk b128 LDS reads + parallel exp; phase2: 14-FMA recurrence,
// h*C -> LDS; phase3: parallel 16-state reduce + gate + coalesced store.
#define SCHUNK 14
#define NCHUNK 14
__global__ __launch_bounds__(256, 3) void k_scan(
    const float* __restrict__ delta, const float* __restrict__ u,
    const float* __restrict__ xdbl, const float* __restrict__ xz,
    const float* __restrict__ Alog, const float* __restrict__ Dp,
    ushort_t* __restrict__ yg, int layer)
{
  int blk = blockIdx.x;
  int kdir = blk / (B_*24);
  int rem = blk % (B_*24);
  int b = rem / 24, dc = rem % 24;
  int tid = threadIdx.x;
  int st = tid & 15, ch = tid >> 4;           // compute mapping
  size_t pl = (size_t)(kdir*DEPTH_+layer)*DIN + dc*16 + ch;
  float a = -expf(Alog[pl*DSTATE + st]);
  size_t rowbase = ((size_t)kdir*B_ + b)*L_;

  int ll = tid >> 4, cc = tid & 15;           // loader/phase3 mapping
  bool ldr = tid < 224;
  float Dv3 = Dp[(size_t)(kdir*DEPTH_+layer)*DIN + dc*16 + cc];

  __shared__ __align__(16) float sd[16][20], su[16][20], sB[16][20],
                                 sC[16][20], sz[16][20];
  __shared__ __align__(16) float sp[SCHUNK][16][20];

  float rd=0.f, ru=0.f, rB=0.f, rC=0.f, rz=0.f;
  if (ldr) {
    size_t r = rowbase + ll;
    rd = delta[r*DIN + dc*16 + cc];
    ru = u[r*DIN + dc*16 + cc];
    rB = xdbl[r*44 + DTR + cc];
    rC = xdbl[r*44 + DTR + DSTATE + cc];
    rz = xz[r*768 + DIN + dc*16 + cc];
  }

  float h = 0.f;
  for (int chk = 0; chk < NCHUNK; ++chk) {
    if (ldr) { sd[cc][ll]=rd; su[cc][ll]=ru; sB[cc][ll]=rB; sC[cc][ll]=rC; sz[cc][ll]=rz; }
    __syncthreads();
    if (chk+1 < NCHUNK && ldr) {
      size_t r = rowbase + (chk+1)*SCHUNK + ll;
      rd = delta[r*DIN + dc*16 + cc];
      ru = u[r*DIN + dc*16 + cc];
      rB = xdbl[r*44 + DTR + cc];
      rC = xdbl[r*44 + DTR + DSTATE + cc];
      rz = xz[r*768 + DIN + dc*16 + cc];
    }
    // phase 1: bulk-load coefficient rows, compute all E (parallel exps)
    float dlv[16], ulv[16], Bvv[16], Cvv[16];
    #pragma unroll
    for (int i = 0; i < 4; ++i) {
      ((float4*)dlv)[i] = ((const float4*)&sd[ch][0])[i];
      ((float4*)ulv)[i] = ((const float4*)&su[ch][0])[i];
      ((float4*)Bvv)[i] = ((const float4*)&sB[st][0])[i];
      ((float4*)Cvv)[i] = ((const float4*)&sC[st][0])[i];
    }
    float E[SCHUNK];
    #pragma unroll
    for (int l = 0; l < SCHUNK; ++l) E[l] = __expf(dlv[l]*a);
    // phase 2: 14-FMA recurrence chain, store h*C
    #pragma unroll
    for (int l = 0; l < SCHUNK; ++l) {
      h = h*E[l] + dlv[l]*ulv[l]*Bvv[l];
      sp[l][ch][st] = h*Cvv[l];
    }
    __syncthreads();
    // phase 3: reduce 16 states per (l, ch), gate, coalesced store
    if (ldr) {
      float pv[16];
      #pragma unroll
      for (int i = 0; i < 4; ++i)
        ((float4*)pv)[i] = ((const float4*)&sp[ll][cc][0])[i];
      float s = 0.f;
      #pragma unroll
      for (int i = 0; i < 16; ++i) s += pv[i];
      float ul = su[cc][ll];
      float z  = sz[cc][ll];
      float yv = (s + ul*Dv3) * (z / (1.f + __expf(-z)));
      yg[(rowbase + chk*SCHUNK + ll)*DIN + dc*16 + cc] = f2bf(yv);
    }
    __syncthreads();
  }
}

// ---------------- merge 4 directions + out_norm LN + head LN --------------
__global__ __launch_bounds__(64) void k_combine(
    const float* __restrict__ hid, const float* __restrict__ res,
    const float* __restrict__ onw, const float* __restrict__ onb,
    const float* __restrict__ hlw, const float* __restrict__ hlb,
    float* __restrict__ ynorm)
{
  int blk = blockIdx.x;
  int b = blk / L_, l = blk % L_;
  int hh = l / W_, ww = l % W_;
  int l1 = ww*W_ + hh;
  size_t r0 = ((size_t)(0*B_+b))*L_ + l;
  size_t r1 = ((size_t)(1*B_+b))*L_ + l1;
  size_t r2 = ((size_t)(2*B_+b))*L_ + (L_-1-l);
  size_t r3 = ((size_t)(3*B_+b))*L_ + (L_-1-l1);
  int lane = threadIdx.x;
  float v[3]; float s = 0.f;
  #pragma unroll
  for (int i=0;i<3;i++){
    int d = lane + i*64;
    float t = hid[r0*D_+d]+res[r0*D_+d] + hid[r1*D_+d]+res[r1*D_+d]
            + hid[r2*D_+d]+res[r2*D_+d] + hid[r3*D_+d]+res[r3*D_+d];
    v[i]=t; s+=t;
  }
  #pragma unroll
  for (int off=32;off;off>>=1) s += __shfl_xor(s,off);
  float m = s*(1.f/D_); float q=0.f;
  #pragma unroll
  for (int i=0;i<3;i++){ float dd=v[i]-m; q+=dd*dd; }
  #pragma unroll
  for (int off=32;off;off>>=1) q += __shfl_xor(q,off);
  float inv = rsqrtf(q*(1.f/D_)+EPS_);
  float v2[3]; s = 0.f;
  #pragma unroll
  for (int i=0;i<3;i++){ int d=lane+i*64; float t=(v[i]-m)*inv*onw[d]+onb[d]; v2[i]=t; s+=t; }
  #pragma unroll
  for (int off=32;off;off>>=1) s += __shfl_xor(s,off);
  float m2 = s*(1.f/D_); q=0.f;
  #pragma unroll
  for (int i=0;i<3;i++){ float dd=v2[i]-m2; q+=dd*dd; }
  #pragma unroll
  for (int off=32;off;off>>=1) q += __shfl_xor(q,off);
  float inv2 = rsqrtf(q*(1.f/D_)+EPS_);
  #pragma unroll
  for (int i=0;i<3;i++){ int d=lane+i*64; ynorm[((size_t)b*L_+l)*D_+d] = (v2[i]-m2)*inv2*hlw[d]+hlb[d]; }
}

// ---------------- mean over L ---------------------------------------------
__global__ __launch_bounds__(192) void k_mean(const float* __restrict__ ynorm, float* __restrict__ ybar)
{
  int b = blockIdx.x, d = threadIdx.x;
  float s = 0.f;
  for (int l = 0; l < L_; ++l) s += ynorm[((size_t)b*L_+l)*D_ + d];
  ybar[b*D_+d] = s * (1.f/L_);
}

// ---------------- classifier head -----------------------------------------
__global__ __launch_bounds__(256) void k_head(
    const float* __restrict__ ybar, const float* __restrict__ hw, const float* __restrict__ hb,
    float* __restrict__ out)
{
  __shared__ float ys[D_];
  int b = blockIdx.x >> 2;
  int c = (blockIdx.x & 3)*256 + threadIdx.x;
  for (int i = threadIdx.x; i < D_; i += 256) ys[i] = ybar[b*D_+i];
  __syncthreads();
  if (c < NCLS_) {
    float acc = hb[c];
    const float* wr = hw + (size_t)c*D_;
    for (int dd = 0; dd < D_; dd += 4) {
      float4 a4 = *reinterpret_cast<const float4*>(&ys[dd]);
      float4 b4 = *reinterpret_cast<const float4*>(&wr[dd]);
      acc += a4.x*b4.x + a4.y*b4.y + a4.z*b4.z + a4.w*b4.w;
    }
    out[(size_t)b*NCLS_ + c] = acc;
  }
}

extern "C" void kernel_launch(void* const* d_in, const int* in_sizes, int n_in,
                              void* d_out, int out_size, void* d_ws, size_t ws_size,
                              hipStream_t stream)
{
  const float* x          = (const float*)d_in[0];
  const float* patch_w    = (const float*)d_in[1];
  const float* patch_b    = (const float*)d_in[2];
  const float* pe_ln_w    = (const float*)d_in[3];
  const float* pe_ln_b    = (const float*)d_in[4];
  const float* ln_w       = (const float*)d_in[5];
  const float* ln_b       = (const float*)d_in[6];
  const float* in_proj_w  = (const float*)d_in[7];
  const float* conv_w     = (const float*)d_in[8];
  const float* conv_b     = (const float*)d_in[9];
  const float* x_proj_w   = (const float*)d_in[10];
  const float* dt_w       = (const float*)d_in[11];
  const float* dt_b       = (const float*)d_in[12];
  const float* A_log      = (const float*)d_in[13];
  const float* Dp         = (const float*)d_in[14];
  const float* out_proj_w = (const float*)d_in[15];
  const float* out_norm_w = (const float*)d_in[16];
  const float* out_norm_b = (const float*)d_in[17];
  const float* head_ln_w  = (const float*)d_in[18];
  const float* head_ln_b  = (const float*)d_in[19];
  const float* head_w     = (const float*)d_in[20];
  const float* head_b     = (const float*)d_in[21];
  float* out = (float*)d_out;

  float* ws = (float*)d_ws;
  float*   hidden   = ws;                         // 1,204,224 f32
  float*   residual = hidden   + 1204224;         // 1,204,224 f32
  float*   xz       = residual + 1204224;         // 4,816,896 f32
  float*   u        = xz       + 4816896;         // 2,408,448 f32
  float*   xdbl     = u        + 2408448;         //   275,968 f32
  float*   delta    = xdbl     + 275968;          // 2,408,448 f32
  ushort_t* yg_bf   = (ushort_t*)(delta + 2408448);        // 2,408,448 ush
  ushort_t* xln_bf  = (ushort_t*)((float*)yg_bf + 1204224);// 1,204,224 ush
  ushort_t* wbf     = (ushort_t*)((float*)xln_bf + 602112);
  ushort_t* pw_bf   = wbf;                        //   147,456 ush
  ushort_t* inw_bf  = wbf + 147456;               // 4,718,592 ush
  ushort_t* outw_bf = inw_bf + 4718592;           // 2,359,296 ush
  ushort_t* xw_bf   = outw_bf + 2359296;          //   786,432 ush (padded [32][64][384])
  // u_bf aliases the delta region (conv writes it; xproj reads it;
  // k_delta overwrites the region afterwards — strictly ordered).
  ushort_t* u_bf    = (ushort_t*)delta;           // 2,408,448 ush
  // patch-phase aliases inside xz (xz not yet written):
  ushort_t* Xp      = (ushort_t*)xz;              // 1,204,224 ush
  float*   C_patch  = xz + 602112;                //   301,056 f32
  // tail aliases inside delta (delta dead after last scan):
  float*   ynorm    = delta;                      //   301,056 f32
  float*   ybar     = delta + 301056;             //     1,536 f32

  // one-time (per call) weight conversions
  k_cvt<<<(147456/4+255)/256, 256, 0, stream>>>(patch_w, pw_bf, 147456/4);
  k_cvt<<<(4718592/4+255)/256, 256, 0, stream>>>(in_proj_w, inw_bf, 4718592/4);
  k_cvt<<<(2359296/4+255)/256, 256, 0, stream>>>(out_proj_w, outw_bf, 2359296/4);
  k_cvt_xw<<<(32*64*384+255)/256, 256, 0, stream>>>(x_proj_w, xw_bf);

  // patch embed: im2col -> mfma gemm -> LN + scatter
  k_im2col<<<(ROWS_PER_DIR*768+255)/256, 256, 0, stream>>>(x, Xp);
  k_gemm_mfma<768><<<dim3(ROWS_PER_DIR/32, D_/32), 64, 0, stream>>>(
      Xp, pw_bf, C_patch, D_, D_, 0, ROWS_PER_DIR);
  k_peln<<<ROWS_PER_DIR, 64, 0, stream>>>(C_patch, patch_b, pe_ln_w, pe_ln_b, hidden, residual);

  for (int layer = 0; layer < DEPTH_; ++layer) {
    k_ln_res<<<M_TOTAL/4, 256, 0, stream>>>(ln_w, ln_b, hidden, residual, xln_bf, layer);
    k_gemm_mfma<192><<<dim3(M_TOTAL/32, 768/32), 64, 0, stream>>>(
        xln_bf, inw_bf + (size_t)layer*768*D_, xz, 768, 768, DEPTH_*768*D_, ROWS_PER_DIR);
    k_conv<<<(M_TOTAL*96+255)/256, 256, 0, stream>>>(xz, conv_w, conv_b, u, u_bf, layer);
    k_gemm_mfma<384><<<dim3(M_TOTAL/32, 2), 64, 0, stream>>>(
        u_bf, xw_bf + (size_t)layer*64*384, xdbl, 44, 44, DEPTH_*64*384, ROWS_PER_DIR);
    k_delta<<<(M_TOTAL*96+255)/256, 256, 0, stream>>>(xdbl, dt_w, dt_b, delta, layer);
    k_scan<<<4*B_*24, 256, 0, stream>>>(delta, u, xdbl, xz, A_log, Dp, yg_bf, layer);
    k_gemm_mfma<384><<<dim3(M_TOTAL/32, D_/32), 64, 0, stream>>>(
        yg_bf, outw_bf + (size_t)layer*D_*DIN, hidden, D_, D_, DEPTH_*D_*DIN, ROWS_PER_DIR);
  }

  k_combine<<<B_*L_, 64, 0, stream>>>(hidden, residual, out_norm_w, out_norm_b,
                                      head_ln_w, head_ln_b, ynorm);
  k_mean<<<B_, 192, 0, stream>>>(ynorm, ybar);
  k_head<<<B_*4, 256, 0, stream>>>(ybar, head_w, head_b, out);
}

// Round 5
// 677.615 us; speedup vs baseline: 3.8250x; 1.0751x over previous
//
#include <hip/hip_runtime.h>

#define B_ 8
#define IMGSZ 224
#define PATCH 16
#define D_ 192
#define DEPTH_ 8
#define H_ 14
#define W_ 14
#define L_ 196
#define DIN 384
#define DSTATE 16
#define DCONV 4
#define DTR 12
#define NCLS_ 1000
#define EPS_ 1e-5f
#define ROWS_PER_DIR (B_*L_)      /* 1568 */
#define M_TOTAL (4*ROWS_PER_DIR)  /* 6272 */

typedef unsigned short ushort_t;
typedef unsigned int uint_t;
typedef __attribute__((ext_vector_type(8)))  short bf16x8;
typedef __attribute__((ext_vector_type(16))) float f32x16;

__device__ __forceinline__ ushort_t f2bf(float f) {
  uint_t u = __builtin_bit_cast(uint_t, f);
  u += 0x7fffu + ((u >> 16) & 1u);          // RNE
  return (ushort_t)(u >> 16);
}

// ------------- one-shot f32->bf16 conversion of the 3 big weight arrays ---
// dst regions are contiguous: [patch 147456][in_proj 4718592][out_proj 2359296]
__global__ __launch_bounds__(256) void k_cvt3(
    const float* __restrict__ s0, const float* __restrict__ s1,
    const float* __restrict__ s2, ushort_t* __restrict__ dst)
{
  int i = blockIdx.x*256 + threadIdx.x;         // float4 index
  if (i >= 1806336) return;
  const float* src;
  int off;
  if (i < 36864)        { src = s0; off = i; }
  else if (i < 1216512) { src = s1; off = i - 36864; }
  else                  { src = s2; off = i - 1216512; }
  float4 v = reinterpret_cast<const float4*>(src)[off];
  ushort4 o;
  o.x = f2bf(v.x); o.y = f2bf(v.y); o.z = f2bf(v.z); o.w = f2bf(v.w);
  reinterpret_cast<ushort4*>(dst)[i] = o;
}

// ---------------- x_proj_w [32][44][384] -> padded bf16 [32][64][384] -----
__global__ __launch_bounds__(256) void k_cvt_xw(const float* __restrict__ src,
                                                ushort_t* __restrict__ dst)
{
  int idx = blockIdx.x*256 + threadIdx.x;
  if (idx >= 32*64*384) return;
  int g = idx / (64*384);
  int r = (idx / 384) % 64;
  int k = idx % 384;
  float v = (r < 44) ? src[((size_t)g*44 + r)*384 + k] : 0.f;
  dst[idx] = f2bf(v);
}

// ---------------- im2col of 16x16 patches -> bf16 [1568][768] -------------
__global__ __launch_bounds__(256) void k_im2col(const float* __restrict__ x,
                                                ushort_t* __restrict__ Xp)
{
  int idx = blockIdx.x*256 + threadIdx.x;
  if (idx >= ROWS_PER_DIR*768) return;
  int row = idx / 768, k = idx - row*768;
  int b = row / L_, l = row - b*L_;
  int hh = l / W_, ww = l - hh*W_;
  int c = k >> 8, rem = k & 255, pi = rem >> 4, pj = rem & 15;
  float v = x[(((size_t)b*3 + c)*IMGSZ + hh*PATCH + pi)*IMGSZ + ww*PATCH + pj];
  Xp[idx] = f2bf(v);
}

// ------- MFMA bf16 GEMM, 32 rows x 64 cols per wave: C = X W^T (f32) ------
template<int KT>
__global__ __launch_bounds__(64) void k_gemm2(
    const ushort_t* __restrict__ X, const ushort_t* __restrict__ W,
    float* __restrict__ C, int N, int nb, int wstride, int rows_per_dir)
{
  int row0 = blockIdx.x*32, col0 = blockIdx.y*64;
  int dir = row0 / rows_per_dir;
  const ushort_t* Wp = W + (size_t)dir*wstride;
  int l = threadIdx.x;
  int r31 = l & 31, khalf = (l >> 5)*8;
  const ushort_t* aptr  = X  + (size_t)(row0 + r31)*KT + khalf;
  const ushort_t* b0ptr = Wp + (size_t)(col0 + r31)*KT + khalf;
  const ushort_t* b1ptr = b0ptr + (size_t)32*KT;
  f32x16 acc00 = {}, acc01 = {}, acc10 = {}, acc11 = {};
  #pragma unroll
  for (int k = 0; k < KT; k += 32) {
    bf16x8 a0 = *reinterpret_cast<const bf16x8*>(aptr + k);
    bf16x8 a1 = *reinterpret_cast<const bf16x8*>(aptr + k + 16);
    bf16x8 b00 = *reinterpret_cast<const bf16x8*>(b0ptr + k);
    bf16x8 b01 = *reinterpret_cast<const bf16x8*>(b0ptr + k + 16);
    bf16x8 b10 = *reinterpret_cast<const bf16x8*>(b1ptr + k);
    bf16x8 b11 = *reinterpret_cast<const bf16x8*>(b1ptr + k + 16);
    acc00 = __builtin_amdgcn_mfma_f32_32x32x16_bf16(a0, b00, acc00, 0, 0, 0);
    acc01 = __builtin_amdgcn_mfma_f32_32x32x16_bf16(a1, b01, acc01, 0, 0, 0);
    acc10 = __builtin_amdgcn_mfma_f32_32x32x16_bf16(a0, b10, acc10, 0, 0, 0);
    acc11 = __builtin_amdgcn_mfma_f32_32x32x16_bf16(a1, b11, acc11, 0, 0, 0);
  }
  int c0 = col0 + r31, c1 = col0 + 32 + r31;
  #pragma unroll
  for (int r = 0; r < 16; ++r) {
    int row = (r & 3) + 8*(r >> 2) + 4*(l >> 5);
    float* crow = C + (size_t)(row0 + row)*N;
    if (c0 < nb) crow[c0] = acc00[r] + acc01[r];
    if (c1 < nb) crow[c1] = acc10[r] + acc11[r];
  }
}

// ------- patch LN + layer-0 LN + scatter residual/xln to 4 directions -----
__global__ __launch_bounds__(64) void k_peln(
    const float* __restrict__ Cp, const float* __restrict__ pb,
    const float* __restrict__ plw, const float* __restrict__ plb,
    const float* __restrict__ lnw, const float* __restrict__ lnb,
    float* __restrict__ residual, ushort_t* __restrict__ xln)
{
  int blk = blockIdx.x;            // b*L + l
  int b = blk / L_, l = blk - b*L_;
  int hh = l / W_, ww = l - hh*W_;
  int lane = threadIdx.x;
  float v[3]; float s = 0.f;
  #pragma unroll
  for (int i = 0; i < 3; ++i) {
    int d = lane + i*64;
    float t = Cp[(size_t)blk*D_ + d] + pb[d];
    v[i] = t; s += t;
  }
  #pragma unroll
  for (int off = 32; off; off >>= 1) s += __shfl_xor(s, off);
  float m = s*(1.f/D_); float q = 0.f;
  #pragma unroll
  for (int i = 0; i < 3; ++i) { float dd = v[i]-m; q += dd*dd; }
  #pragma unroll
  for (int off = 32; off; off >>= 1) q += __shfl_xor(q, off);
  float inv = rsqrtf(q*(1.f/D_)+EPS_);
  // token embedding nv
  float nv[3]; s = 0.f;
  #pragma unroll
  for (int i = 0; i < 3; ++i) {
    int d = lane + i*64;
    nv[i] = (v[i]-m)*inv*plw[d] + plb[d];
    s += nv[i];
  }
  // layer-0 LN stats over nv
  #pragma unroll
  for (int off = 32; off; off >>= 1) s += __shfl_xor(s, off);
  float m2 = s*(1.f/D_); q = 0.f;
  #pragma unroll
  for (int i = 0; i < 3; ++i) { float dd = nv[i]-m2; q += dd*dd; }
  #pragma unroll
  for (int off = 32; off; off >>= 1) q += __shfl_xor(q, off);
  float inv2 = rsqrtf(q*(1.f/D_)+EPS_);
  int l1 = ww*W_ + hh;
  size_t rr[4];
  rr[0] = ((size_t)(0*B_+b))*L_ + l;
  rr[1] = ((size_t)(1*B_+b))*L_ + l1;
  rr[2] = ((size_t)(2*B_+b))*L_ + (L_-1-l);
  rr[3] = ((size_t)(3*B_+b))*L_ + (L_-1-l1);
  #pragma unroll
  for (int i = 0; i < 3; ++i) {
    int d = lane + i*64;
    float nrm = (nv[i]-m2)*inv2;
    #pragma unroll
    for (int k = 0; k < 4; ++k) {
      residual[rr[k]*D_+d] = nv[i];
      xln[rr[k]*D_+d] = f2bf(nrm*lnw[(size_t)(k*DEPTH_)*D_+d] + lnb[(size_t)(k*DEPTH_)*D_+d]);
    }
  }
}

// ---------------- causal depthwise conv (k=4) + bias + SiLU, float4 -------
__global__ __launch_bounds__(256) void k_conv(
    const float* __restrict__ xz, const float* __restrict__ cw, const float* __restrict__ cb,
    float* __restrict__ u, ushort_t* __restrict__ ub, int layer)
{
  int idx = blockIdx.x*256 + threadIdx.x;
  if (idx >= M_TOTAL*96) return;
  int row = idx / 96, d4 = (idx - row*96)*4;
  int kdir = row / ROWS_PER_DIR;
  int l = row % L_;
  size_t pbase = (size_t)(kdir*DEPTH_+layer)*DIN + d4;
  const float* cwp = cw + pbase*DCONV;
  float wv[16];
  #pragma unroll
  for (int i = 0; i < 4; ++i)
    ((float4*)wv)[i] = ((const float4*)cwp)[i];
  float4 bias = *reinterpret_cast<const float4*>(&cb[pbase]);
  float acc[4] = {bias.x, bias.y, bias.z, bias.w};
  #pragma unroll
  for (int t = 0; t < DCONV; ++t) {
    int ll = l - 3 + t;
    if (ll >= 0) {
      float4 xv = *reinterpret_cast<const float4*>(&xz[((size_t)row + (ll - l))*768 + d4]);
      acc[0] += xv.x * wv[0*4 + t];
      acc[1] += xv.y * wv[1*4 + t];
      acc[2] += xv.z * wv[2*4 + t];
      acc[3] += xv.w * wv[3*4 + t];
    }
  }
  float4 o; ushort4 ob;
  o.x = acc[0] / (1.f + __expf(-acc[0]));
  o.y = acc[1] / (1.f + __expf(-acc[1]));
  o.z = acc[2] / (1.f + __expf(-acc[2]));
  o.w = acc[3] / (1.f + __expf(-acc[3]));
  ob.x = f2bf(o.x); ob.y = f2bf(o.y); ob.z = f2bf(o.z); ob.w = f2bf(o.w);
  *reinterpret_cast<float4*>(&u[(size_t)row*DIN + d4]) = o;
  *reinterpret_cast<ushort4*>(&ub[(size_t)row*DIN + d4]) = ob;
}

// ------- selective scan with inline delta-proj + skip(D) + SiLU(z) gate ---
// block: 16 channels x 16 states; grid: 4*8*24; chunked, shuffle-free.
#define SCHUNK 14
#define NCHUNK 14
__global__ __launch_bounds__(256, 3) void k_scan(
    const float* __restrict__ u, const float* __restrict__ xdbl,
    const float* __restrict__ xz,
    const float* __restrict__ Alog, const float* __restrict__ Dp,
    const float* __restrict__ dtw, const float* __restrict__ dtb,
    ushort_t* __restrict__ yg, int layer)
{
  int blk = blockIdx.x;
  int kdir = blk / (B_*24);
  int rem = blk % (B_*24);
  int b = rem / 24, dc = rem % 24;
  int tid = threadIdx.x;
  int st = tid & 15, ch = tid >> 4;           // compute mapping
  size_t pl = (size_t)(kdir*DEPTH_+layer)*DIN + dc*16 + ch;
  float a = -expf(Alog[pl*DSTATE + st]);
  size_t rowbase = ((size_t)kdir*B_ + b)*L_;

  int ll = tid >> 4, cc = tid & 15;           // loader/phase3 mapping
  bool ldr = tid < 224;
  size_t plc = (size_t)(kdir*DEPTH_+layer)*DIN + dc*16 + cc;
  float Dv3 = Dp[plc];
  // per-thread dt weights (channel cc) for inline delta
  float dwt[12]; float dbias = dtb[plc];
  #pragma unroll
  for (int i = 0; i < 3; ++i)
    ((float4*)dwt)[i] = ((const float4*)(dtw + plc*DTR))[i];

  __shared__ __align__(16) float sd[16][20], su[16][20], sB[16][20],
                                 sC[16][20], sz[16][20];
  __shared__ __align__(16) float sp[SCHUNK][16][20];

  float rd=0.f, ru=0.f, rB=0.f, rC=0.f, rz=0.f;
  if (ldr) {
    size_t r = rowbase + ll;
    float xv[12];
    #pragma unroll
    for (int i = 0; i < 3; ++i) ((float4*)xv)[i] = ((const float4*)(xdbl + r*44))[i];
    float acc = dbias;
    #pragma unroll
    for (int t = 0; t < DTR; ++t) acc += xv[t]*dwt[t];
    rd = (acc > 20.f) ? acc : log1pf(__expf(acc));
    ru = u[r*DIN + dc*16 + cc];
    rB = xdbl[r*44 + DTR + cc];
    rC = xdbl[r*44 + DTR + DSTATE + cc];
    rz = xz[r*768 + DIN + dc*16 + cc];
  }

  float h = 0.f;
  for (int chk = 0; chk < NCHUNK; ++chk) {
    if (ldr) { sd[cc][ll]=rd; su[cc][ll]=ru; sB[cc][ll]=rB; sC[cc][ll]=rC; sz[cc][ll]=rz; }
    __syncthreads();
    if (chk+1 < NCHUNK && ldr) {
      size_t r = rowbase + (chk+1)*SCHUNK + ll;
      float xv[12];
      #pragma unroll
      for (int i = 0; i < 3; ++i) ((float4*)xv)[i] = ((const float4*)(xdbl + r*44))[i];
      float acc = dbias;
      #pragma unroll
      for (int t = 0; t < DTR; ++t) acc += xv[t]*dwt[t];
      rd = (acc > 20.f) ? acc : log1pf(__expf(acc));
      ru = u[r*DIN + dc*16 + cc];
      rB = xdbl[r*44 + DTR + cc];
      rC = xdbl[r*44 + DTR + DSTATE + cc];
      rz = xz[r*768 + DIN + dc*16 + cc];
    }
    // phase 1: bulk-load coefficient rows, compute all E (parallel exps)
    float dlv[16], ulv[16], Bvv[16], Cvv[16];
    #pragma unroll
    for (int i = 0; i < 4; ++i) {
      ((float4*)dlv)[i] = ((const float4*)&sd[ch][0])[i];
      ((float4*)ulv)[i] = ((const float4*)&su[ch][0])[i];
      ((float4*)Bvv)[i] = ((const float4*)&sB[st][0])[i];
      ((float4*)Cvv)[i] = ((const float4*)&sC[st][0])[i];
    }
    float E[SCHUNK];
    #pragma unroll
    for (int l = 0; l < SCHUNK; ++l) E[l] = __expf(dlv[l]*a);
    // phase 2: 14-FMA recurrence chain, store h*C
    #pragma unroll
    for (int l = 0; l < SCHUNK; ++l) {
      h = h*E[l] + dlv[l]*ulv[l]*Bvv[l];
      sp[l][ch][st] = h*Cvv[l];
    }
    __syncthreads();
    // phase 3: reduce 16 states per (l, ch), gate, coalesced store
    if (ldr) {
      float pv[16];
      #pragma unroll
      for (int i = 0; i < 4; ++i)
        ((float4*)pv)[i] = ((const float4*)&sp[ll][cc][0])[i];
      float s = 0.f;
      #pragma unroll
      for (int i = 0; i < 16; ++i) s += pv[i];
      float ul = su[cc][ll];
      float z  = sz[cc][ll];
      float yv = (s + ul*Dv3) * (z / (1.f + __expf(-z)));
      yg[(rowbase + chk*SCHUNK + ll)*DIN + dc*16 + cc] = f2bf(yv);
    }
    __syncthreads();
  }
}

// ------ fused out_proj GEMM + residual add + LN(layer+1) -> xln_bf --------
// grid 196 blocks x 384 threads (6 waves, one 32x32 col tile each)
template<int LAST>
__global__ __launch_bounds__(384) void k_outln(
    const ushort_t* __restrict__ X, const ushort_t* __restrict__ W,
    float* __restrict__ residual,
    const float* __restrict__ lnw, const float* __restrict__ lnb,
    ushort_t* __restrict__ xln, int layer)
{
  int row0 = blockIdx.x*32;
  int dir = row0 / ROWS_PER_DIR;
  const ushort_t* Wp = W + (size_t)dir*(DEPTH_*D_*DIN);
  int tid = threadIdx.x;
  int wv = tid >> 6;           // 0..5 -> col tile
  int l  = tid & 63;
  int col0 = wv*32;
  int r31 = l & 31, khalf = (l >> 5)*8;
  const ushort_t* aptr = X  + (size_t)(row0 + r31)*DIN + khalf;
  const ushort_t* bptr = Wp + (size_t)(col0 + r31)*DIN + khalf;
  f32x16 acc0 = {}, acc1 = {};
  #pragma unroll
  for (int k = 0; k < DIN; k += 32) {
    bf16x8 a0 = *reinterpret_cast<const bf16x8*>(aptr + k);
    bf16x8 b0 = *reinterpret_cast<const bf16x8*>(bptr + k);
    bf16x8 a1 = *reinterpret_cast<const bf16x8*>(aptr + k + 16);
    bf16x8 b1 = *reinterpret_cast<const bf16x8*>(bptr + k + 16);
    acc0 = __builtin_amdgcn_mfma_f32_32x32x16_bf16(a0, b0, acc0, 0, 0, 0);
    acc1 = __builtin_amdgcn_mfma_f32_32x32x16_bf16(a1, b1, acc1, 0, 0, 0);
  }
  __shared__ __align__(16) float Cs[32][196];
  __shared__ float sred[32][12], qred[32][12], sm[32], si[32];
  #pragma unroll
  for (int r = 0; r < 16; ++r) {
    int row = (r & 3) + 8*(r >> 2) + 4*(l >> 5);
    Cs[row][col0 + r31] = acc0[r] + acc1[r];
  }
  __syncthreads();
  // epilogue: 32 rows x 12 threads x 16 cols
  int rr = tid / 12, jj = tid - rr*12;
  int c0 = jj*16;
  float* resrow = residual + (size_t)(row0+rr)*D_ + c0;
  float v[16];
  float s = 0.f, q = 0.f;
  #pragma unroll
  for (int i = 0; i < 16; i += 4) {
    float4 rv = *reinterpret_cast<const float4*>(resrow + i);
    float4 cv = *reinterpret_cast<const float4*>(&Cs[rr][c0 + i]);
    v[i+0] = rv.x + cv.x; v[i+1] = rv.y + cv.y;
    v[i+2] = rv.z + cv.z; v[i+3] = rv.w + cv.w;
  }
  #pragma unroll
  for (int i = 0; i < 16; ++i) { s += v[i]; q += v[i]*v[i]; }
  // store residual_new
  #pragma unroll
  for (int i = 0; i < 16; i += 4) {
    float4 o = make_float4(v[i], v[i+1], v[i+2], v[i+3]);
    *reinterpret_cast<float4*>(resrow + i) = o;
  }
  if (!LAST) {
    sred[rr][jj] = s; qred[rr][jj] = q;
    __syncthreads();
    if (tid < 32) {
      float S = 0.f, Q = 0.f;
      #pragma unroll
      for (int j = 0; j < 12; ++j) { S += sred[tid][j]; Q += qred[tid][j]; }
      float m = S*(1.f/D_);
      float var = Q*(1.f/D_) - m*m;
      sm[tid] = m; si[tid] = rsqrtf(var + EPS_);
    }
    __syncthreads();
    float m = sm[rr], inv = si[rr];
    const float* w = lnw + (size_t)(dir*DEPTH_ + layer + 1)*D_ + c0;
    const float* bb = lnb + (size_t)(dir*DEPTH_ + layer + 1)*D_ + c0;
    ushort_t* xrow = xln + (size_t)(row0+rr)*D_ + c0;
    #pragma unroll
    for (int i = 0; i < 16; ++i)
      xrow[i] = f2bf((v[i]-m)*inv*w[i] + bb[i]);
  }
}

// ---------------- merge 4 directions + out_norm LN + head LN --------------
__global__ __launch_bounds__(64) void k_combine(
    const float* __restrict__ res,
    const float* __restrict__ onw, const float* __restrict__ onb,
    const float* __restrict__ hlw, const float* __restrict__ hlb,
    float* __restrict__ ynorm)
{
  int blk = blockIdx.x;
  int b = blk / L_, l = blk % L_;
  int hh = l / W_, ww = l % W_;
  int l1 = ww*W_ + hh;
  size_t r0 = ((size_t)(0*B_+b))*L_ + l;
  size_t r1 = ((size_t)(1*B_+b))*L_ + l1;
  size_t r2 = ((size_t)(2*B_+b))*L_ + (L_-1-l);
  size_t r3 = ((size_t)(3*B_+b))*L_ + (L_-1-l1);
  int lane = threadIdx.x;
  float v[3]; float s = 0.f;
  #pragma unroll
  for (int i=0;i<3;i++){
    int d = lane + i*64;
    float t = res[r0*D_+d] + res[r1*D_+d] + res[r2*D_+d] + res[r3*D_+d];
    v[i]=t; s+=t;
  }
  #pragma unroll
  for (int off=32;off;off>>=1) s += __shfl_xor(s,off);
  float m = s*(1.f/D_); float q=0.f;
  #pragma unroll
  for (int i=0;i<3;i++){ float dd=v[i]-m; q+=dd*dd; }
  #pragma unroll
  for (int off=32;off;off>>=1) q += __shfl_xor(q,off);
  float inv = rsqrtf(q*(1.f/D_)+EPS_);
  float v2[3]; s = 0.f;
  #pragma unroll
  for (int i=0;i<3;i++){ int d=lane+i*64; float t=(v[i]-m)*inv*onw[d]+onb[d]; v2[i]=t; s+=t; }
  #pragma unroll
  for (int off=32;off;off>>=1) s += __shfl_xor(s,off);
  float m2 = s*(1.f/D_); q=0.f;
  #pragma unroll
  for (int i=0;i<3;i++){ float dd=v2[i]-m2; q+=dd*dd; }
  #pragma unroll
  for (int off=32;off;off>>=1) q += __shfl_xor(q,off);
  float inv2 = rsqrtf(q*(1.f/D_)+EPS_);
  #pragma unroll
  for (int i=0;i<3;i++){ int d=lane+i*64; ynorm[((size_t)b*L_+l)*D_+d] = (v2[i]-m2)*inv2*hlw[d]+hlb[d]; }
}

// ---------------- mean over L ---------------------------------------------
__global__ __launch_bounds__(192) void k_mean(const float* __restrict__ ynorm, float* __restrict__ ybar)
{
  int b = blockIdx.x, d = threadIdx.x;
  float s = 0.f;
  for (int l = 0; l < L_; ++l) s += ynorm[((size_t)b*L_+l)*D_ + d];
  ybar[b*D_+d] = s * (1.f/L_);
}

// ---------------- classifier head -----------------------------------------
__global__ __launch_bounds__(256) void k_head(
    const float* __restrict__ ybar, const float* __restrict__ hw, const float* __restrict__ hb,
    float* __restrict__ out)
{
  __shared__ float ys[D_];
  int b = blockIdx.x >> 2;
  int c = (blockIdx.x & 3)*256 + threadIdx.x;
  for (int i = threadIdx.x; i < D_; i += 256) ys[i] = ybar[b*D_+i];
  __syncthreads();
  if (c < NCLS_) {
    float acc = hb[c];
    const float* wr = hw + (size_t)c*D_;
    for (int dd = 0; dd < D_; dd += 4) {
      float4 a4 = *reinterpret_cast<const float4*>(&ys[dd]);
      float4 b4 = *reinterpret_cast<const float4*>(&wr[dd]);
      acc += a4.x*b4.x + a4.y*b4.y + a4.z*b4.z + a4.w*b4.w;
    }
    out[(size_t)b*NCLS_ + c] = acc;
  }
}

extern "C" void kernel_launch(void* const* d_in, const int* in_sizes, int n_in,
                              void* d_out, int out_size, void* d_ws, size_t ws_size,
                              hipStream_t stream)
{
  const float* x          = (const float*)d_in[0];
  const float* patch_w    = (const float*)d_in[1];
  const float* patch_b    = (const float*)d_in[2];
  const float* pe_ln_w    = (const float*)d_in[3];
  const float* pe_ln_b    = (const float*)d_in[4];
  const float* ln_w       = (const float*)d_in[5];
  const float* ln_b       = (const float*)d_in[6];
  const float* in_proj_w  = (const float*)d_in[7];
  const float* conv_w     = (const float*)d_in[8];
  const float* conv_b     = (const float*)d_in[9];
  const float* x_proj_w   = (const float*)d_in[10];
  const float* dt_w       = (const float*)d_in[11];
  const float* dt_b       = (const float*)d_in[12];
  const float* A_log      = (const float*)d_in[13];
  const float* Dp         = (const float*)d_in[14];
  const float* out_proj_w = (const float*)d_in[15];
  const float* out_norm_w = (const float*)d_in[16];
  const float* out_norm_b = (const float*)d_in[17];
  const float* head_ln_w  = (const float*)d_in[18];
  const float* head_ln_b  = (const float*)d_in[19];
  const float* head_w     = (const float*)d_in[20];
  const float* head_b     = (const float*)d_in[21];
  float* out = (float*)d_out;

  float* ws = (float*)d_ws;
  float*   residual = ws;                         // 1,204,224 f32
  float*   xz       = residual + 1204224;         // 4,816,896 f32
  float*   u        = xz + 4816896;               // 2,408,448 f32
  float*   xdbl     = u + 2408448;                //   275,968 f32
  ushort_t* u_bf    = (ushort_t*)(xdbl + 275968); // 2,408,448 ush
  ushort_t* yg_bf   = u_bf + 2408448;             // 2,408,448 ush
  ushort_t* xln_bf  = yg_bf + 2408448;            // 1,204,224 ush
  ushort_t* wbf     = xln_bf + 1204224;
  ushort_t* pw_bf   = wbf;                        //   147,456 ush
  ushort_t* inw_bf  = wbf + 147456;               // 4,718,592 ush
  ushort_t* outw_bf = inw_bf + 4718592;           // 2,359,296 ush
  ushort_t* xw_bf   = outw_bf + 2359296;          //   786,432 ush
  // patch-phase aliases inside xz (xz not yet written):
  ushort_t* Xp      = (ushort_t*)xz;              // 1,204,224 ush
  float*   C_patch  = xz + 602112;                //   301,056 f32
  // tail aliases inside u (dead after last scan):
  float*   ynorm    = u;                          //   301,056 f32
  float*   ybar     = u + 301056;                 //     1,536 f32

  // weight conversions
  k_cvt3<<<(1806336+255)/256, 256, 0, stream>>>(patch_w, in_proj_w, out_proj_w, wbf);
  k_cvt_xw<<<(32*64*384+255)/256, 256, 0, stream>>>(x_proj_w, xw_bf);

  // patch embed: im2col -> mfma gemm -> double LN + scatter
  k_im2col<<<(ROWS_PER_DIR*768+255)/256, 256, 0, stream>>>(x, Xp);
  k_gemm2<768><<<dim3(ROWS_PER_DIR/32, 3), 64, 0, stream>>>(
      Xp, pw_bf, C_patch, D_, D_, 0, ROWS_PER_DIR);
  k_peln<<<ROWS_PER_DIR, 64, 0, stream>>>(C_patch, patch_b, pe_ln_w, pe_ln_b,
                                          ln_w, ln_b, residual, xln_bf);

  for (int layer = 0; layer < DEPTH_; ++layer) {
    k_gemm2<192><<<dim3(M_TOTAL/32, 12), 64, 0, stream>>>(
        xln_bf, inw_bf + (size_t)layer*768*D_, xz, 768, 768, DEPTH_*768*D_, ROWS_PER_DIR);
    k_conv<<<(M_TOTAL*96+255)/256, 256, 0, stream>>>(xz, conv_w, conv_b, u, u_bf, layer);
    k_gemm2<384><<<dim3(M_TOTAL/32, 1), 64, 0, stream>>>(
        u_bf, xw_bf + (size_t)layer*64*384, xdbl, 44, 44, DEPTH_*64*384, ROWS_PER_DIR);
    k_scan<<<4*B_*24, 256, 0, stream>>>(u, xdbl, xz, A_log, Dp, dt_w, dt_b, yg_bf, layer);
    if (layer < DEPTH_-1)
      k_outln<0><<<M_TOTAL/32, 384, 0, stream>>>(
          yg_bf, outw_bf, residual, ln_w, ln_b, xln_bf, layer);
    else
      k_outln<1><<<M_TOTAL/32, 384, 0, stream>>>(
          yg_bf, outw_bf, residual, ln_w, ln_b, xln_bf, layer);
  }

  k_combine<<<B_*L_, 64, 0, stream>>>(residual, out_norm_w, out_norm_b,
                                      head_ln_w, head_ln_b, ynorm);
  k_mean<<<B_, 192, 0, stream>>>(ynorm, ybar);
  k_head<<<B_*4, 256, 0, stream>>>(ybar, head_w, head_b, out);
}